// Round 7
// baseline (1074.608 us; speedup 1.0000x reference)
//
#include <hip/hip_runtime.h>
#include <cstddef>

typedef __bf16 bf16;
typedef __bf16 bf16x8 __attribute__((ext_vector_type(8)));
typedef float f32x4 __attribute__((ext_vector_type(4)));

#define D 512
#define DFF 2048
#define MFMA __builtin_amdgcn_mfma_f32_16x16x32_bf16

__device__ __forceinline__ float load_any(const void* p, size_t i, int f) {
  return f ? ((const float*)p)[i] : (float)((const bf16*)p)[i];
}

__device__ __forceinline__ float fast_gelu(float x) {
  float y = 1.5957691216f * (x + 0.044715f * x * x * x);
  y = fminf(y, 80.0f);
  float e = __expf(y);
  return x * e / (e + 1.0f);
}

__global__ void detect_dtype(const unsigned* __restrict__ x, int* flag) {
  __shared__ int cnt;
  if (threadIdx.x == 0) cnt = 0;
  __syncthreads();
  int local = 0;
  for (int i = threadIdx.x; i < 32768; i += 256) {
    unsigned e = (x[i] >> 7) & 0xFFu;
    if (e >= 160u) local++;
  }
  atomicAdd(&cnt, local);
  __syncthreads();
  if (threadIdx.x == 0) *flag = (cnt > 100) ? 1 : 0;
}

__global__ __launch_bounds__(256)
void conv_to_bf16(const void* __restrict__ src, bf16* __restrict__ dst, int n,
                  const int* __restrict__ flag) {
  const int f = *flag;
  for (int i = blockIdx.x * 256 + threadIdx.x; i < n; i += gridDim.x * 256)
    dst[i] = (bf16)load_any(src, i, f);
}

struct CDesc { const void* src; unsigned long long off; bf16* dst; int n; int pad; };
struct CPack { CDesc d[40]; };
__global__ __launch_bounds__(256)
void conv_batch(CPack P, const int* __restrict__ flag) {
  const CDesc& c = P.d[blockIdx.z];
  const int f = *flag;
  for (int i = blockIdx.x * 256 + threadIdx.x; i < c.n; i += gridDim.x * 256)
    c.dst[i] = (bf16)load_any(c.src, c.off + i, f);
}

struct TDesc { const void* src; unsigned long long off; bf16* dst; };
struct TPack { TDesc d[20]; };
__global__ __launch_bounds__(256)
void transpose_b(TPack P, int Kd, int Nd, const int* __restrict__ flag) {
  __shared__ bf16 tile[64][65];
  const TDesc& t = P.d[blockIdx.z];
  const int f = *flag;
  int tx = threadIdx.x & 63, ty = threadIdx.x >> 6;
  int nb = blockIdx.x * 64, kb = blockIdx.y * 64;
  #pragma unroll
  for (int r = ty; r < 64; r += 4)
    tile[r][tx] = (bf16)load_any(t.src, t.off + (size_t)(kb + r) * Nd + nb + tx, f);
  __syncthreads();
  #pragma unroll
  for (int r = ty; r < 64; r += 4)
    t.dst[(size_t)(nb + r) * Kd + kb + tx] = tile[tx][r];
}

// K,V [B*S,512] -> frag-major Kf,Vf [(b*8+h)][kt][nt][c][lane][8]
__global__ __launch_bounds__(256)
void prep_kv(const bf16* __restrict__ K, const bf16* __restrict__ V,
             bf16* __restrict__ Kf, bf16* __restrict__ Vf, int S)
{
  __shared__ bf16 tile[64][72];
  const int kt = blockIdx.x, h = blockIdx.y, b = blockIdx.z;
  const int t = threadIdx.x;
  const int r = t >> 2, g = t & 3;
  const size_t srcrow = ((size_t)(b * S + kt * 64 + r)) * D + h * 64 + g * 16;
  const size_t bh = (size_t)(b * 8 + h);
  const size_t tbase = (bh * (S >> 6) + kt) * 4096;

  bf16x8 k0 = *(const bf16x8*)(K + srcrow);
  bf16x8 k1 = *(const bf16x8*)(K + srcrow + 8);
  const int nt = r >> 4, m15 = r & 15;
  const int c = g >> 1, qq = (g & 1) * 2;
  *(bf16x8*)(Kf + tbase + (((nt * 2 + c) * 64) + qq * 16 + m15) * 8)       = k0;
  *(bf16x8*)(Kf + tbase + (((nt * 2 + c) * 64) + (qq + 1) * 16 + m15) * 8) = k1;

  bf16x8 v0 = *(const bf16x8*)(V + srcrow);
  bf16x8 v1 = *(const bf16x8*)(V + srcrow + 8);
  #pragma unroll
  for (int u = 0; u < 8; u++) {
    tile[g * 16 + u][r]     = v0[u];
    tile[g * 16 + 8 + u][r] = v1[u];
  }
  __syncthreads();
  #pragma unroll
  for (int s = 0; s < 2; s++) {
    int i = t * 2 + s;
    int lane = i & 63, ntc = i >> 6;
    int vq = lane >> 4, vm = lane & 15;
    int vnt = ntc >> 1, vc = ntc & 1;
    bf16x8 o = *(const bf16x8*)(&tile[vnt * 16 + vm][vc * 32 + vq * 8]);
    *(bf16x8*)(Vf + tbase + (size_t)i * 8) = o;
  }
}

__device__ __forceinline__ void gload_lds16(const bf16* g, bf16* l) {
  __builtin_amdgcn_global_load_lds((const __attribute__((address_space(1))) void*)g,
                                   (__attribute__((address_space(3))) void*)l,
                                   16, 0, 0);
}

// XCD-aware block swizzle: same A row-band -> same XCD (heuristic xcd = lin%8).
__device__ __forceinline__ void swizzle_bm_bn(int& bm, int& bn) {
  int lin = blockIdx.y * gridDim.x + blockIdx.x;
  if ((gridDim.y & 7) == 0) {
    int xcd = lin & 7, j = lin >> 3;
    bn = j % gridDim.x;
    bm = xcd + 8 * (j / gridDim.x);
  } else {
    bn = blockIdx.x; bm = blockIdx.y;
  }
}

// Epilogue macro: repack acc tile through LDS (stride 136), store dwordx4.
// VAL(i,j,r) must yield the final float for (row wm+i*16+q*4+r, col wn+j*16+l15).
#define EPILOGUE_STORE(smem, Cbase, rowstride, colbase, VAL)                      \
  {                                                                               \
    _Pragma("unroll")                                                             \
    for (int half = 0; half < 2; half++) {                                        \
      __syncthreads();                                                            \
      if ((wm >> 6) == half) {                                                    \
        _Pragma("unroll")                                                         \
        for (int j = 0; j < 4; j++)                                               \
          _Pragma("unroll")                                                       \
          for (int i = 0; i < 4; i++)                                             \
            _Pragma("unroll")                                                     \
            for (int r = 0; r < 4; r++)                                           \
              smem[(i * 16 + q * 4 + r) * 136 + wn + j * 16 + l15] =              \
                  (bf16)(VAL(i, j, r));                                           \
      }                                                                           \
      __syncthreads();                                                            \
      const int srow = tid >> 2, scc = (tid & 3) * 32;                            \
      _Pragma("unroll")                                                           \
      for (int k = 0; k < 4; k++) {                                               \
        bf16x8 v = *(const bf16x8*)(smem + srow * 136 + scc + k * 8);             \
        *(bf16x8*)(Cbase + (size_t)(bm * 128 + half * 64 + srow) * (rowstride) +  \
                   (colbase) + scc + k * 8) = v;                                  \
      }                                                                           \
    }                                                                             \
  }

// C[M,N] = act(A @ B + bias), B as BT[N,K].
__global__ __launch_bounds__(256, 2)
void gemm_bt(const bf16* __restrict__ A, const bf16* __restrict__ BT,
             const bf16* __restrict__ bias, bf16* __restrict__ C,
             int M, int N, int K, int act)
{
  __shared__ bf16 smem[64 * 136];
  bf16* As = smem;
  bf16* Bs = smem + 4096;
  const int tid = threadIdx.x;
  int bm, bn; swizzle_bm_bn(bm, bn);
  const int wid = tid >> 6, lane = tid & 63;
  const int wm = (wid >> 1) << 6, wn = (wid & 1) << 6;
  const int l15 = lane & 15, q = lane >> 4;

  f32x4 acc[4][4] = {};

  const bf16* ag = A + (size_t)(bm * 128 + (tid >> 2)) * K + (tid & 3) * 8;
  const bf16* bg = BT + (size_t)(bn * 128 + (tid >> 2)) * K + (tid & 3) * 8;
  const size_t rstep = (size_t)64 * K;
  bf16* asl = As + tid * 8;
  bf16* bsl = Bs + tid * 8;

  for (int k0 = 0; k0 < K; k0 += 32) {
    __syncthreads();
    gload_lds16(ag + k0,          asl);
    gload_lds16(ag + k0 + rstep,  asl + 256 * 8);
    gload_lds16(bg + k0,          bsl);
    gload_lds16(bg + k0 + rstep,  bsl + 256 * 8);
    __syncthreads();

    bf16x8 af[4], bq[4];
    #pragma unroll
    for (int i = 0; i < 4; i++)
      af[i] = *(const bf16x8*)(As + (wm + i * 16 + l15) * 32 + q * 8);
    #pragma unroll
    for (int j = 0; j < 4; j++)
      bq[j] = *(const bf16x8*)(Bs + (wn + j * 16 + l15) * 32 + q * 8);
    #pragma unroll
    for (int i = 0; i < 4; i++)
      #pragma unroll
      for (int j = 0; j < 4; j++)
        acc[i][j] = MFMA(af[i], bq[j], acc[i][j], 0, 0, 0);
  }

  float bcol[4];
  #pragma unroll
  for (int j = 0; j < 4; j++) bcol[j] = (float)bias[bn * 128 + wn + j * 16 + l15];

#define GBT_VAL(i, j, r)                                                   \
  (act ? fast_gelu(acc[i][j][r] + bcol[j]) : (acc[i][j][r] + bcol[j]))
  EPILOGUE_STORE(smem, C, N, bn * 128, GBT_VAL)
#undef GBT_VAL
}

// K-split GEMM (ksplit=2): N==512. split0 -> P0 (+bias), split1 -> P1.
__global__ __launch_bounds__(256, 2)
void gemm_ks(const bf16* __restrict__ A, const bf16* __restrict__ BT,
             const bf16* __restrict__ bias, bf16* __restrict__ P0,
             bf16* __restrict__ P1, int M, int N, int K)
{
  __shared__ bf16 smem[64 * 136];
  bf16* As = smem;
  bf16* Bs = smem + 4096;
  const int tid = threadIdx.x;
  int bm, bnl; swizzle_bm_bn(bm, bnl);
  const int bn = bnl >> 1, split = bnl & 1;
  const int Kh = K >> 1, kbase = split * Kh;
  const int wid = tid >> 6, lane = tid & 63;
  const int wm = (wid >> 1) << 6, wn = (wid & 1) << 6;
  const int l15 = lane & 15, q = lane >> 4;

  f32x4 acc[4][4] = {};

  const bf16* ag = A + (size_t)(bm * 128 + (tid >> 2)) * K + kbase + (tid & 3) * 8;
  const bf16* bg = BT + (size_t)(bn * 128 + (tid >> 2)) * K + kbase + (tid & 3) * 8;
  const size_t rstep = (size_t)64 * K;
  bf16* asl = As + tid * 8;
  bf16* bsl = Bs + tid * 8;

  for (int k0 = 0; k0 < Kh; k0 += 32) {
    __syncthreads();
    gload_lds16(ag + k0,          asl);
    gload_lds16(ag + k0 + rstep,  asl + 256 * 8);
    gload_lds16(bg + k0,          bsl);
    gload_lds16(bg + k0 + rstep,  bsl + 256 * 8);
    __syncthreads();

    bf16x8 af[4], bq[4];
    #pragma unroll
    for (int i = 0; i < 4; i++)
      af[i] = *(const bf16x8*)(As + (wm + i * 16 + l15) * 32 + q * 8);
    #pragma unroll
    for (int j = 0; j < 4; j++)
      bq[j] = *(const bf16x8*)(Bs + (wn + j * 16 + l15) * 32 + q * 8);
    #pragma unroll
    for (int i = 0; i < 4; i++)
      #pragma unroll
      for (int j = 0; j < 4; j++)
        acc[i][j] = MFMA(af[i], bq[j], acc[i][j], 0, 0, 0);
  }

  bf16* Cp = split ? P1 : P0;
  float bcol[4];
  #pragma unroll
  for (int j = 0; j < 4; j++)
    bcol[j] = split ? 0.0f : (float)bias[bn * 128 + wn + j * 16 + l15];

#define GKS_VAL(i, j, r) (acc[i][j][r] + bcol[j])
  EPILOGUE_STORE(smem, Cp, 512, bn * 128, GKS_VAL)
#undef GKS_VAL
}

// Segmented-output GEMM: N = 512*nseg, segment s -> Os (row stride 512).
__global__ __launch_bounds__(256, 2)
void gemm_seg(const bf16* __restrict__ A, const bf16* __restrict__ BT,
              const bf16* __restrict__ bias,
              bf16* __restrict__ O0, bf16* __restrict__ O1, bf16* __restrict__ O2,
              int M, int K)
{
  __shared__ bf16 smem[64 * 136];
  bf16* As = smem;
  bf16* Bs = smem + 4096;
  const int tid = threadIdx.x;
  int bm, bn; swizzle_bm_bn(bm, bn);
  const int wid = tid >> 6, lane = tid & 63;
  const int wm = (wid >> 1) << 6, wn = (wid & 1) << 6;
  const int l15 = lane & 15, q = lane >> 4;

  f32x4 acc[4][4] = {};

  const bf16* ag = A + (size_t)(bm * 128 + (tid >> 2)) * K + (tid & 3) * 8;
  const bf16* bg = BT + (size_t)(bn * 128 + (tid >> 2)) * K + (tid & 3) * 8;
  const size_t rstep = (size_t)64 * K;
  bf16* asl = As + tid * 8;
  bf16* bsl = Bs + tid * 8;

  for (int k0 = 0; k0 < K; k0 += 32) {
    __syncthreads();
    gload_lds16(ag + k0,          asl);
    gload_lds16(ag + k0 + rstep,  asl + 256 * 8);
    gload_lds16(bg + k0,          bsl);
    gload_lds16(bg + k0 + rstep,  bsl + 256 * 8);
    __syncthreads();

    bf16x8 af[4], bq[4];
    #pragma unroll
    for (int i = 0; i < 4; i++)
      af[i] = *(const bf16x8*)(As + (wm + i * 16 + l15) * 32 + q * 8);
    #pragma unroll
    for (int j = 0; j < 4; j++)
      bq[j] = *(const bf16x8*)(Bs + (wn + j * 16 + l15) * 32 + q * 8);
    #pragma unroll
    for (int i = 0; i < 4; i++)
      #pragma unroll
      for (int j = 0; j < 4; j++)
        acc[i][j] = MFMA(af[i], bq[j], acc[i][j], 0, 0, 0);
  }

  const int seg = (bn * 128) >> 9;
  bf16* Cp = (seg == 0) ? O0 : ((seg == 1) ? O1 : O2);
  const int colb = seg << 9;
  float bcol[4];
  #pragma unroll
  for (int j = 0; j < 4; j++) bcol[j] = (float)bias[bn * 128 + wn + j * 16 + l15];

#define GSEG_VAL(i, j, r) (acc[i][j][r] + bcol[j])
  EPILOGUE_STORE(smem, Cp, 512, bn * 128 - colb, GSEG_VAL)
#undef GSEG_VAL
}

// ---------------------------------------------------------------- flash attn
__global__ __launch_bounds__(256, 2)
void flash_attn(const bf16* __restrict__ Q, const bf16* __restrict__ Kf,
                const bf16* __restrict__ Vf, bf16* __restrict__ O,
                int L, int S, int causal)
{
  __shared__ bf16 PL[4][32 * 72];
  const int tid = threadIdx.x, wid = tid >> 6, lane = tid & 63;
  const int m15 = lane & 15, q = lane >> 4;
  const int b = blockIdx.z, h = blockIdx.y;
  const int wq = blockIdx.x * 128 + wid * 32;

  bf16x8 aq[2][2];
  #pragma unroll
  for (int qh = 0; qh < 2; qh++) {
    const bf16* qp = Q + ((size_t)(b * L + wq + qh * 16 + m15)) * D + h * 64 + q * 8;
    aq[qh][0] = *(const bf16x8*)(qp);
    aq[qh][1] = *(const bf16x8*)(qp + 32);
  }
  const size_t bh = (size_t)(b * 8 + h);
  const bf16* kfb = Kf + bh * ((size_t)S * 64);
  const bf16* vfb = Vf + bh * ((size_t)S * 64);

  f32x4 acco[2][4] = {};
  float ls[2][4] = {};

  const int ktmax = causal ? ((wq + 95) >> 6) : (S >> 6);

  bf16x8 kf[4][2];
  #pragma unroll
  for (int nt = 0; nt < 4; nt++)
    #pragma unroll
    for (int c = 0; c < 2; c++)
      kf[nt][c] = *(const bf16x8*)(kfb + ((nt * 2 + c) * 64 + lane) * 8);

  bf16* pl = &PL[wid][0];

  for (int kt = 0; kt < ktmax; kt++) {
    bf16x8 vf[4][2];
    const bf16* vc = vfb + (size_t)kt * 4096;
    #pragma unroll
    for (int nt = 0; nt < 4; nt++)
      #pragma unroll
      for (int c = 0; c < 2; c++)
        vf[nt][c] = *(const bf16x8*)(vc + ((nt * 2 + c) * 64 + lane) * 8);

    f32x4 sc[2][4];
    #pragma unroll
    for (int qh = 0; qh < 2; qh++)
      #pragma unroll
      for (int nt = 0; nt < 4; nt++) {
        f32x4 z = {};
        z = MFMA(aq[qh][0], kf[nt][0], z, 0, 0, 0);
        z = MFMA(aq[qh][1], kf[nt][1], z, 0, 0, 0);
        sc[qh][nt] = z;
      }

    {
      const int knext = (kt + 1 < ktmax) ? kt + 1 : kt;
      const bf16* kc = kfb + (size_t)knext * 4096;
      #pragma unroll
      for (int nt = 0; nt < 4; nt++)
        #pragma unroll
        for (int c = 0; c < 2; c++)
          kf[nt][c] = *(const bf16x8*)(kc + ((nt * 2 + c) * 64 + lane) * 8);
    }

    const bool mask = causal && (kt == ktmax - 1);
    #pragma unroll
    for (int qh = 0; qh < 2; qh++)
      #pragma unroll
      for (int nt = 0; nt < 4; nt++)
        #pragma unroll
        for (int r = 0; r < 4; r++) {
          float s = sc[qh][nt][r] * 0.125f;
          if (mask) {
            int kg = kt * 64 + nt * 16 + m15;
            int qg = wq + qh * 16 + q * 4 + r;
            if (kg > qg) s = -1e30f;
          }
          float p = __expf(s);
          ls[qh][r] += p;
          pl[(qh * 16 + q * 4 + r) * 72 + nt * 16 + m15] = (bf16)p;
        }

    #pragma unroll
    for (int qh = 0; qh < 2; qh++) {
      bf16x8 pa0 = *(const bf16x8*)(pl + (qh * 16 + m15) * 72 + q * 8);
      bf16x8 pa1 = *(const bf16x8*)(pl + (qh * 16 + m15) * 72 + 32 + q * 8);
      #pragma unroll
      for (int nt = 0; nt < 4; nt++) {
        acco[qh][nt] = MFMA(pa0, vf[nt][0], acco[qh][nt], 0, 0, 0);
        acco[qh][nt] = MFMA(pa1, vf[nt][1], acco[qh][nt], 0, 0, 0);
      }
    }
  }

  #pragma unroll
  for (int qh = 0; qh < 2; qh++)
    #pragma unroll
    for (int r = 0; r < 4; r++) {
      float v = ls[qh][r];
      v += __shfl_xor(v, 1); v += __shfl_xor(v, 2);
      v += __shfl_xor(v, 4); v += __shfl_xor(v, 8);
      ls[qh][r] = 1.0f / v;
    }

  // repack O through wave-private LDS (P tile is dead), store vectorized
  #pragma unroll
  for (int qh = 0; qh < 2; qh++)
    #pragma unroll
    for (int nt = 0; nt < 4; nt++)
      #pragma unroll
      for (int r = 0; r < 4; r++)
        pl[(qh * 16 + q * 4 + r) * 72 + nt * 16 + m15] =
            (bf16)(acco[qh][nt][r] * ls[qh][r]);

  const int orow = lane >> 1, occ = (lane & 1) * 32;
  bf16* ob = O + ((size_t)(b * L + wq + orow)) * D + h * 64 + occ;
  #pragma unroll
  for (int k = 0; k < 4; k++)
    *(bf16x8*)(ob + k * 8) = *(const bf16x8*)(pl + orow * 72 + occ + k * 8);
}

// Y = LN(X0 (+X1) (+R)) * g + be. X1 nullable (K-split partial sum).
__global__ __launch_bounds__(256)
void add_ln(const bf16* __restrict__ X0, const bf16* __restrict__ X1,
            const bf16* __restrict__ R,
            const bf16* __restrict__ g, const bf16* __restrict__ be,
            bf16* __restrict__ Y, int hasR)
{
  __shared__ float red[4];
  const int row = blockIdx.x, tid = threadIdx.x;
  const bf16* x = X0 + (size_t)row * D;
  float v0 = (float)x[tid], v1 = (float)x[tid + 256];
  if (X1 != nullptr) {
    const bf16* p = X1 + (size_t)row * D;
    v0 += (float)p[tid]; v1 += (float)p[tid + 256];
  }
  if (hasR) {
    const bf16* r = R + (size_t)row * D;
    v0 += (float)r[tid]; v1 += (float)r[tid + 256];
  }
  float s = v0 + v1;
  #pragma unroll
  for (int o = 32; o > 0; o >>= 1) s += __shfl_down(s, o);
  if ((tid & 63) == 0) red[tid >> 6] = s;
  __syncthreads();
  const float mean = (red[0] + red[1] + red[2] + red[3]) * (1.0f / 512.0f);
  __syncthreads();
  const float d0 = v0 - mean, d1 = v1 - mean;
  float sq = d0 * d0 + d1 * d1;
  #pragma unroll
  for (int o = 32; o > 0; o >>= 1) sq += __shfl_down(sq, o);
  if ((tid & 63) == 0) red[tid >> 6] = sq;
  __syncthreads();
  const float var = (red[0] + red[1] + red[2] + red[3]) * (1.0f / 512.0f);
  const float rstd = rsqrtf(var + 1e-5f);
  bf16* y = Y + (size_t)row * D;
  y[tid]       = (bf16)(d0 * rstd * (float)g[tid]       + (float)be[tid]);
  y[tid + 256] = (bf16)(d1 * rstd * (float)g[tid + 256] + (float)be[tid + 256]);
}

// Y = LN( LN(X0+X1+R)*g1+b1 ) * g2 + b2   (fused double-LN, X1/R required)
__global__ __launch_bounds__(256)
void add_lnln(const bf16* __restrict__ X0, const bf16* __restrict__ X1,
              const bf16* __restrict__ R,
              const bf16* __restrict__ g1, const bf16* __restrict__ b1,
              const bf16* __restrict__ g2, const bf16* __restrict__ b2,
              bf16* __restrict__ Y)
{
  __shared__ float red[4];
  const int row = blockIdx.x, tid = threadIdx.x;
  const size_t o = (size_t)row * D;
  float v0 = (float)X0[o + tid] + (float)X1[o + tid] + (float)R[o + tid];
  float v1 = (float)X0[o + tid + 256] + (float)X1[o + tid + 256] + (float)R[o + tid + 256];

  float s = v0 + v1;
  #pragma unroll
  for (int q = 32; q > 0; q >>= 1) s += __shfl_down(s, q);
  if ((tid & 63) == 0) red[tid >> 6] = s;
  __syncthreads();
  const float mean = (red[0] + red[1] + red[2] + red[3]) * (1.0f / 512.0f);
  __syncthreads();
  float d0 = v0 - mean, d1 = v1 - mean;
  float sq = d0 * d0 + d1 * d1;
  #pragma unroll
  for (int q = 32; q > 0; q >>= 1) sq += __shfl_down(sq, q);
  if ((tid & 63) == 0) red[tid >> 6] = sq;
  __syncthreads();
  const float var = (red[0] + red[1] + red[2] + red[3]) * (1.0f / 512.0f);
  const float rstd = rsqrtf(var + 1e-5f);
  float u0 = d0 * rstd * (float)g1[tid]       + (float)b1[tid];
  float u1 = d1 * rstd * (float)g1[tid + 256] + (float)b1[tid + 256];

  __syncthreads();
  float s2 = u0 + u1;
  #pragma unroll
  for (int q = 32; q > 0; q >>= 1) s2 += __shfl_down(s2, q);
  if ((tid & 63) == 0) red[tid >> 6] = s2;
  __syncthreads();
  const float mean2 = (red[0] + red[1] + red[2] + red[3]) * (1.0f / 512.0f);
  __syncthreads();
  float e0 = u0 - mean2, e1 = u1 - mean2;
  float sq2 = e0 * e0 + e1 * e1;
  #pragma unroll
  for (int q = 32; q > 0; q >>= 1) sq2 += __shfl_down(sq2, q);
  if ((tid & 63) == 0) red[tid >> 6] = sq2;
  __syncthreads();
  const float var2 = (red[0] + red[1] + red[2] + red[3]) * (1.0f / 512.0f);
  const float rstd2 = rsqrtf(var2 + 1e-5f);
  bf16* y = Y + o;
  y[tid]       = (bf16)(e0 * rstd2 * (float)g2[tid]       + (float)b2[tid]);
  y[tid + 256] = (bf16)(e1 * rstd2 * (float)g2[tid + 256] + (float)b2[tid + 256]);
}

__global__ __launch_bounds__(256)
void proj_out(const bf16* __restrict__ X, const bf16* __restrict__ Wp,
              const bf16* __restrict__ bp, void* __restrict__ out,
              const int* __restrict__ flag)
{
  __shared__ float part[4][64];
  const int rb = blockIdx.x;
  const int b = rb >> 8, t = rb & 255;
  const int tid = threadIdx.x;
  const bf16* x = X + ((size_t)(b * 512 + 256 + t)) * D;
  const int c = tid & 63, seg = tid >> 6;
  float acc = 0.f;
  for (int k = seg * 128; k < seg * 128 + 128; k++)
    acc += (float)x[k] * (float)Wp[(size_t)k * 64 + c];
  part[seg][c] = acc;
  __syncthreads();
  if (tid < 64) {
    float v = part[0][tid] + part[1][tid] + part[2][tid] + part[3][tid] + (float)bp[tid];
    size_t idx = (size_t)rb * 64 + tid;
    if (*flag) ((float*)out)[idx] = v;
    else       ((bf16*)out)[idx] = (bf16)v;
  }
}

extern "C" void kernel_launch(void* const* d_in, const int* in_sizes, int n_in,
                              void* d_out, int out_size, void* d_ws, size_t ws_size,
                              hipStream_t stream)
{
  (void)in_sizes; (void)n_in; (void)out_size; (void)ws_size;

  char* wsb = (char*)d_ws;
  int* flag = (int*)wsb;
  bf16* w = (bf16*)(wsb + 256);
  size_t off = 0;
  auto alloc = [&](size_t n) { bf16* p = w + off; off += n; return p; };

  bf16* eQKVT = alloc(3 * (size_t)1536 * D);
  bf16* eWoT  = alloc(3 * (size_t)D * D);
  bf16* eW1T  = alloc(3 * (size_t)D * DFF);
  bf16* eW2T  = alloc(3 * (size_t)D * DFF);
  bf16* dQKVT = alloc((size_t)1536 * D);
  bf16* sWoT  = alloc((size_t)D * D);
  bf16* cWqT  = alloc((size_t)D * D);
  bf16* cKVT  = alloc((size_t)1024 * D);
  bf16* cWoT  = alloc((size_t)D * D);
  bf16* dW1T  = alloc((size_t)D * DFF);
  bf16* dW2T  = alloc((size_t)D * DFF);
  bf16* pW    = alloc((size_t)D * 64);
  bf16* e_qkvb  = alloc(3 * 1536);
  bf16* d_sqkvb = alloc(1536);
  bf16* d_ckvb  = alloc(1024);
  bf16* c_ebo = alloc(3 * D);
  bf16* c_eb1 = alloc(3 * DFF); bf16* c_eb2 = alloc(3 * D);
  bf16* c_eg1 = alloc(3 * D);   bf16* c_ebe1 = alloc(3 * D);
  bf16* c_eg2 = alloc(3 * D);   bf16* c_ebe2 = alloc(3 * D);
  bf16* c_eng = alloc(D);       bf16* c_enb = alloc(D);
  bf16* c_dsbo = alloc(D);
  bf16* c_dcbq = alloc(D);      bf16* c_dcbo = alloc(D);
  bf16* c_db1 = alloc(DFF);     bf16* c_db2 = alloc(D);
  bf16* c_dg1 = alloc(D);  bf16* c_dbe1 = alloc(D);
  bf16* c_dg2 = alloc(D);  bf16* c_dbe2 = alloc(D);
  bf16* c_dg3 = alloc(D);  bf16* c_dbe3 = alloc(D);
  bf16* c_dng = alloc(D);  bf16* c_dnb = alloc(D);
  bf16* c_pb  = alloc(64);
  bf16* xe   = alloc((size_t)8192 * D);
  bf16* enco = alloc((size_t)8192 * D);
  bf16* xd0  = alloc((size_t)4096 * D);
  bf16* xd   = alloc((size_t)4096 * D);
  bf16* qb   = alloc((size_t)8192 * D);
  bf16* kb   = alloc((size_t)8192 * D);
  bf16* vb   = alloc((size_t)8192 * D);
  bf16* t0   = alloc((size_t)8192 * D);
  bf16* t1   = alloc((size_t)8192 * D);
  bf16* mid  = qb;

  const dim3 tb(256);

  detect_dtype<<<dim3(1), tb, 0, stream>>>((const unsigned*)d_in[1], flag);

  conv_to_bf16<<<dim3(1024), tb, 0, stream>>>(d_in[1], xe, 8 * 1024 * D, flag);
  conv_to_bf16<<<dim3(1024), tb, 0, stream>>>(d_in[0], xd0, 8 * 512 * D, flag);

  {
    CPack P{};
    int n = 0;
    auto add = [&](int idx, unsigned long long o, bf16* dst, int cnt) {
      P.d[n++] = {d_in[idx], o, dst, cnt, 0};
    };
    add(9, 0, c_ebo, 1536);
    add(11, 0, c_eb1, 6144);  add(13, 0, c_eb2, 1536);
    add(14, 0, c_eg1, 1536);  add(15, 0, c_ebe1, 1536);
    add(16, 0, c_eg2, 1536);  add(17, 0, c_ebe2, 1536);
    add(18, 0, c_eng, 512);   add(19, 0, c_enb, 512);
    add(27, 0, c_dsbo, 512);
    add(29, 0, c_dcbq, 512);  add(35, 0, c_dcbo, 512);
    add(37, 0, c_db1, 2048);  add(39, 0, c_db2, 512);
    add(40, 0, c_dg1, 512);   add(41, 0, c_dbe1, 512);
    add(42, 0, c_dg2, 512);   add(43, 0, c_dbe2, 512);
    add(44, 0, c_dg3, 512);   add(45, 0, c_dbe3, 512);
    add(46, 0, c_dng, 512);   add(47, 0, c_dnb, 512);
    add(48, 0, pW, D * 64);   add(49, 0, c_pb, 64);
    for (int l = 0; l < 3; l++) {
      add(3, (unsigned long long)l * D, e_qkvb + l * 1536, 512);
      add(5, (unsigned long long)l * D, e_qkvb + l * 1536 + 512, 512);
      add(7, (unsigned long long)l * D, e_qkvb + l * 1536 + 1024, 512);
    }
    add(21, 0, d_sqkvb, 512); add(23, 0, d_sqkvb + 512, 512); add(25, 0, d_sqkvb + 1024, 512);
    add(31, 0, d_ckvb, 512);  add(33, 0, d_ckvb + 512, 512);
    conv_batch<<<dim3(24, 1, n), tb, 0, stream>>>(P, flag);
  }

  {
    TPack P{};
    int n = 0;
    for (int l = 0; l < 3; l++) {
      unsigned long long wo = (unsigned long long)l * D * D;
      bf16* dst = eQKVT + (size_t)l * 1536 * D;
      P.d[n++] = {d_in[2], wo, dst};
      P.d[n++] = {d_in[4], wo, dst + 512 * D};
      P.d[n++] = {d_in[6], wo, dst + 1024 * D};
      P.d[n++] = {d_in[8], wo, eWoT + wo};
    }
    P.d[n++] = {d_in[20], 0, dQKVT};
    P.d[n++] = {d_in[22], 0, dQKVT + 512 * D};
    P.d[n++] = {d_in[24], 0, dQKVT + 1024 * D};
    P.d[n++] = {d_in[26], 0, sWoT};
    P.d[n++] = {d_in[28], 0, cWqT};
    P.d[n++] = {d_in[30], 0, cKVT};
    P.d[n++] = {d_in[32], 0, cKVT + 512 * D};
    P.d[n++] = {d_in[34], 0, cWoT};
    transpose_b<<<dim3(8, 8, n), tb, 0, stream>>>(P, D, D, flag);
  }
  {
    TPack P{};
    for (int l = 0; l < 3; l++)
      P.d[l] = {d_in[10], (unsigned long long)l * D * DFF, eW1T + (size_t)l * D * DFF};
    P.d[3] = {d_in[36], 0, dW1T};
    transpose_b<<<dim3(32, 8, 4), tb, 0, stream>>>(P, D, DFF, flag);
  }
  {
    TPack P{};
    for (int l = 0; l < 3; l++)
      P.d[l] = {d_in[12], (unsigned long long)l * D * DFF, eW2T + (size_t)l * D * DFF};
    P.d[3] = {d_in[38], 0, dW2T};
    transpose_b<<<dim3(8, 32, 4), tb, 0, stream>>>(P, DFF, D, flag);
  }

  auto G = [&](const bf16* A, const bf16* BT, const bf16* bias, bf16* C,
               int M, int N, int K, int act) {
    gemm_bt<<<dim3(N / 128, M / 128), tb, 0, stream>>>(A, BT, bias, C, M, N, K, act);
  };
  auto KS = [&](const bf16* A, const bf16* BT, const bf16* bias,
                bf16* P0, bf16* P1, int M, int K) {
    gemm_ks<<<dim3(8, M / 128), tb, 0, stream>>>(A, BT, bias, P0, P1, M, 512, K);
  };
  auto GS = [&](const bf16* A, const bf16* BT, const bf16* bias,
                bf16* O0, bf16* O1, bf16* O2, int M, int N, int K) {
    gemm_seg<<<dim3(N / 128, M / 128), tb, 0, stream>>>(A, BT, bias, O0, O1, O2, M, K);
  };
  auto PK = [&](const bf16* Kp, const bf16* Vp, bf16* Kfp, bf16* Vfp, int S) {
    prep_kv<<<dim3(S / 64, 8, 8), tb, 0, stream>>>(Kp, Vp, Kfp, Vfp, S);
  };
  auto FA = [&](const bf16* Qp, const bf16* Kfp, const bf16* Vfp, bf16* Op,
                int L, int S, int causal) {
    flash_attn<<<dim3(L / 128, 8, 8), tb, 0, stream>>>(Qp, Kfp, Vfp, Op, L, S, causal);
  };
  auto LN = [&](const bf16* X0, const bf16* X1, const bf16* R,
                const bf16* g, const bf16* be, bf16* Y, int hasR, int M) {
    add_ln<<<dim3(M), tb, 0, stream>>>(X0, X1, R, g, be, Y, hasR);
  };

  // ---- encoder: B=8, S=1024 ----
  const int Me = 8192;
  for (int l = 0; l < 3; l++) {
    const size_t wo = (size_t)l * D * D, fo = (size_t)l * D * DFF;
    GS(xe, eQKVT + (size_t)l * 1536 * D, e_qkvb + l * 1536, qb, kb, vb, Me, 1536, D);
    PK(kb, vb, t1, enco, 1024);
    FA(qb, t1, enco, t0, 1024, 1024, 0);
    KS(t0, eWoT + wo, c_ebo + l * D, t1, enco, Me, 512);
    LN(t1, enco, xe, c_eg1 + l * D, c_ebe1 + l * D, xe, 1, Me);
    G(xe, eW1T + fo, c_eb1 + l * DFF, mid, Me, DFF, D, 1);
    KS(mid, eW2T + fo, c_eb2 + l * D, t1, enco, Me, 2048);
    if (l < 2)
      LN(t1, enco, xe, c_eg2 + l * D, c_ebe2 + l * D, xe, 1, Me);
    else
      add_lnln<<<dim3(Me), tb, 0, stream>>>(t1, enco, xe, c_eg2 + 2 * D,
                                            c_ebe2 + 2 * D, c_eng, c_enb, enco);
  }

  // ---- decoder: B=8, L=512 ----
  const int Md = 4096;
  GS(xd0, dQKVT, d_sqkvb, qb, kb, vb, Md, 1536, D);
  PK(kb, vb, t1, xd, 512);
  FA(qb, t1, xd, t0, 512, 512, 1);
  KS(t0, sWoT, c_dsbo, t1, vb, Md, 512);
  LN(t1, vb, xd0, c_dg1, c_dbe1, xd, 1, Md);
  G(xd, cWqT, c_dcbq, qb, Md, D, D, 0);
  GS(enco, cKVT, d_ckvb, kb, vb, nullptr, Me, 1024, D);
  PK(kb, vb, t1, enco, 1024);
  FA(qb, t1, enco, t0, 512, 1024, 0);
  KS(t0, cWoT, c_dcbo, t1, vb, Md, 512);
  LN(t1, vb, xd, c_dg2, c_dbe2, xd, 1, Md);
  G(xd, dW1T, c_db1, mid, Md, DFF, D, 1);
  KS(mid, dW2T, c_db2, t1, vb, Md, 2048);
  add_lnln<<<dim3(Md), tb, 0, stream>>>(t1, vb, xd, c_dg3, c_dbe3, c_dng, c_dnb, xd);
  proj_out<<<dim3(2048), tb, 0, stream>>>(xd, pW, c_pb, d_out, flag);
}

// Round 8
// 921.440 us; speedup vs baseline: 1.1662x; 1.1662x over previous
//
#include <hip/hip_runtime.h>
#include <cstddef>

typedef __bf16 bf16;
typedef __bf16 bf16x8 __attribute__((ext_vector_type(8)));
typedef float f32x4 __attribute__((ext_vector_type(4)));

#define D 512
#define DFF 2048
#define MFMA __builtin_amdgcn_mfma_f32_16x16x32_bf16

__device__ __forceinline__ float load_any(const void* p, size_t i, int f) {
  return f ? ((const float*)p)[i] : (float)((const bf16*)p)[i];
}

// tanh-form GELU via single exp: x*sigmoid(1.5958(x+0.044715x^3)); |err|<3e-3.
__device__ __forceinline__ float fast_gelu(float x) {
  float y = 1.5957691216f * (x + 0.044715f * x * x * x);
  y = fminf(y, 80.0f);
  float e = __expf(y);
  return x * e / (e + 1.0f);
}

__global__ void detect_dtype(const unsigned* __restrict__ x, int* flag) {
  __shared__ int cnt;
  if (threadIdx.x == 0) cnt = 0;
  __syncthreads();
  int local = 0;
  for (int i = threadIdx.x; i < 32768; i += 256) {
    unsigned e = (x[i] >> 7) & 0xFFu;
    if (e >= 160u) local++;
  }
  atomicAdd(&cnt, local);
  __syncthreads();
  if (threadIdx.x == 0) *flag = (cnt > 100) ? 1 : 0;
}

__global__ __launch_bounds__(256)
void conv_to_bf16(const void* __restrict__ src, bf16* __restrict__ dst, int n,
                  const int* __restrict__ flag) {
  const int f = *flag;
  for (int i = blockIdx.x * 256 + threadIdx.x; i < n; i += gridDim.x * 256)
    dst[i] = (bf16)load_any(src, i, f);
}

struct CDesc { const void* src; unsigned long long off; bf16* dst; int n; int pad; };
struct CPack { CDesc d[40]; };
__global__ __launch_bounds__(256)
void conv_batch(CPack P, const int* __restrict__ flag) {
  const CDesc& c = P.d[blockIdx.z];
  const int f = *flag;
  for (int i = blockIdx.x * 256 + threadIdx.x; i < c.n; i += gridDim.x * 256)
    c.dst[i] = (bf16)load_any(c.src, c.off + i, f);
}

struct TDesc { const void* src; unsigned long long off; bf16* dst; };
struct TPack { TDesc d[20]; };
__global__ __launch_bounds__(256)
void transpose_b(TPack P, int Kd, int Nd, const int* __restrict__ flag) {
  __shared__ bf16 tile[64][65];
  const TDesc& t = P.d[blockIdx.z];
  const int f = *flag;
  int tx = threadIdx.x & 63, ty = threadIdx.x >> 6;
  int nb = blockIdx.x * 64, kb = blockIdx.y * 64;
  #pragma unroll
  for (int r = ty; r < 64; r += 4)
    tile[r][tx] = (bf16)load_any(t.src, t.off + (size_t)(kb + r) * Nd + nb + tx, f);
  __syncthreads();
  #pragma unroll
  for (int r = ty; r < 64; r += 4)
    t.dst[(size_t)(nb + r) * Kd + kb + tx] = tile[tx][r];
}

// K,V [B*S,512] -> frag-major Kf,Vf [(b*8+h)][kt][nt][c][lane][8]
__global__ __launch_bounds__(256)
void prep_kv(const bf16* __restrict__ K, const bf16* __restrict__ V,
             bf16* __restrict__ Kf, bf16* __restrict__ Vf, int S)
{
  __shared__ bf16 tile[64][72];
  const int kt = blockIdx.x, h = blockIdx.y, b = blockIdx.z;
  const int t = threadIdx.x;
  const int r = t >> 2, g = t & 3;
  const size_t srcrow = ((size_t)(b * S + kt * 64 + r)) * D + h * 64 + g * 16;
  const size_t bh = (size_t)(b * 8 + h);
  const size_t tbase = (bh * (S >> 6) + kt) * 4096;

  bf16x8 k0 = *(const bf16x8*)(K + srcrow);
  bf16x8 k1 = *(const bf16x8*)(K + srcrow + 8);
  const int nt = r >> 4, m15 = r & 15;
  const int c = g >> 1, qq = (g & 1) * 2;
  *(bf16x8*)(Kf + tbase + (((nt * 2 + c) * 64) + qq * 16 + m15) * 8)       = k0;
  *(bf16x8*)(Kf + tbase + (((nt * 2 + c) * 64) + (qq + 1) * 16 + m15) * 8) = k1;

  bf16x8 v0 = *(const bf16x8*)(V + srcrow);
  bf16x8 v1 = *(const bf16x8*)(V + srcrow + 8);
  #pragma unroll
  for (int u = 0; u < 8; u++) {
    tile[g * 16 + u][r]     = v0[u];
    tile[g * 16 + 8 + u][r] = v1[u];
  }
  __syncthreads();
  #pragma unroll
  for (int s = 0; s < 2; s++) {
    int i = t * 2 + s;
    int lane = i & 63, ntc = i >> 6;
    int vq = lane >> 4, vm = lane & 15;
    int vnt = ntc >> 1, vc = ntc & 1;
    bf16x8 o = *(const bf16x8*)(&tile[vnt * 16 + vm][vc * 32 + vq * 8]);
    *(bf16x8*)(Vf + tbase + (size_t)i * 8) = o;
  }
}

__device__ __forceinline__ void gload_lds16(const bf16* g, bf16* l) {
  __builtin_amdgcn_global_load_lds((const __attribute__((address_space(1))) void*)g,
                                   (__attribute__((address_space(3))) void*)l,
                                   16, 0, 0);
}

// XCD-aware block swizzle: same A row-band -> same XCD (heuristic xcd = lin%8).
__device__ __forceinline__ void swizzle_bm_bn(int& bm, int& bn) {
  int lin = blockIdx.y * gridDim.x + blockIdx.x;
  if ((gridDim.y & 7) == 0) {
    int xcd = lin & 7, j = lin >> 3;
    bn = j % gridDim.x;
    bm = xcd + 8 * (j / gridDim.x);
  } else {
    bn = blockIdx.x; bm = blockIdx.y;
  }
}

// C[M,N] = act(A @ B + bias), B as BT[N,K]. Scalar epilogue (round-6 form:
// LDS-repack variant regressed — extra barriers + VGPR pressure, r7 post-mortem).
__global__ __launch_bounds__(256, 2)
void gemm_bt(const bf16* __restrict__ A, const bf16* __restrict__ BT,
             const bf16* __restrict__ bias, bf16* __restrict__ C,
             int M, int N, int K, int act)
{
  __shared__ bf16 As[128 * 32];
  __shared__ bf16 Bs[128 * 32];
  const int tid = threadIdx.x;
  int bm, bn; swizzle_bm_bn(bm, bn);
  const int wid = tid >> 6, lane = tid & 63;
  const int wm = (wid >> 1) << 6, wn = (wid & 1) << 6;
  const int l15 = lane & 15, q = lane >> 4;

  f32x4 acc[4][4] = {};

  const bf16* ag = A + (size_t)(bm * 128 + (tid >> 2)) * K + (tid & 3) * 8;
  const bf16* bg = BT + (size_t)(bn * 128 + (tid >> 2)) * K + (tid & 3) * 8;
  const size_t rstep = (size_t)64 * K;
  bf16* asl = As + tid * 8;
  bf16* bsl = Bs + tid * 8;

  for (int k0 = 0; k0 < K; k0 += 32) {
    __syncthreads();
    gload_lds16(ag + k0,          asl);
    gload_lds16(ag + k0 + rstep,  asl + 256 * 8);
    gload_lds16(bg + k0,          bsl);
    gload_lds16(bg + k0 + rstep,  bsl + 256 * 8);
    __syncthreads();

    bf16x8 af[4], bq[4];
    #pragma unroll
    for (int i = 0; i < 4; i++)
      af[i] = *(const bf16x8*)(As + (wm + i * 16 + l15) * 32 + q * 8);
    #pragma unroll
    for (int j = 0; j < 4; j++)
      bq[j] = *(const bf16x8*)(Bs + (wn + j * 16 + l15) * 32 + q * 8);
    #pragma unroll
    for (int i = 0; i < 4; i++)
      #pragma unroll
      for (int j = 0; j < 4; j++)
        acc[i][j] = MFMA(af[i], bq[j], acc[i][j], 0, 0, 0);
  }

  #pragma unroll
  for (int j = 0; j < 4; j++) {
    int gcol = bn * 128 + wn + j * 16 + l15;
    float bv = (float)bias[gcol];
    #pragma unroll
    for (int i = 0; i < 4; i++) {
      int grow = bm * 128 + wm + i * 16 + q * 4;
      #pragma unroll
      for (int r = 0; r < 4; r++) {
        float v = acc[i][j][r] + bv;
        if (act == 1) v = fast_gelu(v);
        C[(size_t)(grow + r) * N + gcol] = (bf16)v;
      }
    }
  }
}

// K-split GEMM (ksplit=2): N==512. split0 -> P0 (+bias), split1 -> P1.
__global__ __launch_bounds__(256, 2)
void gemm_ks(const bf16* __restrict__ A, const bf16* __restrict__ BT,
             const bf16* __restrict__ bias, bf16* __restrict__ P0,
             bf16* __restrict__ P1, int M, int N, int K)
{
  __shared__ bf16 As[128 * 32];
  __shared__ bf16 Bs[128 * 32];
  const int tid = threadIdx.x;
  int bm, bnl; swizzle_bm_bn(bm, bnl);
  const int bn = bnl >> 1, split = bnl & 1;
  const int Kh = K >> 1, kbase = split * Kh;
  const int wid = tid >> 6, lane = tid & 63;
  const int wm = (wid >> 1) << 6, wn = (wid & 1) << 6;
  const int l15 = lane & 15, q = lane >> 4;

  f32x4 acc[4][4] = {};

  const bf16* ag = A + (size_t)(bm * 128 + (tid >> 2)) * K + kbase + (tid & 3) * 8;
  const bf16* bg = BT + (size_t)(bn * 128 + (tid >> 2)) * K + kbase + (tid & 3) * 8;
  const size_t rstep = (size_t)64 * K;
  bf16* asl = As + tid * 8;
  bf16* bsl = Bs + tid * 8;

  for (int k0 = 0; k0 < Kh; k0 += 32) {
    __syncthreads();
    gload_lds16(ag + k0,          asl);
    gload_lds16(ag + k0 + rstep,  asl + 256 * 8);
    gload_lds16(bg + k0,          bsl);
    gload_lds16(bg + k0 + rstep,  bsl + 256 * 8);
    __syncthreads();

    bf16x8 af[4], bq[4];
    #pragma unroll
    for (int i = 0; i < 4; i++)
      af[i] = *(const bf16x8*)(As + (wm + i * 16 + l15) * 32 + q * 8);
    #pragma unroll
    for (int j = 0; j < 4; j++)
      bq[j] = *(const bf16x8*)(Bs + (wn + j * 16 + l15) * 32 + q * 8);
    #pragma unroll
    for (int i = 0; i < 4; i++)
      #pragma unroll
      for (int j = 0; j < 4; j++)
        acc[i][j] = MFMA(af[i], bq[j], acc[i][j], 0, 0, 0);
  }

  bf16* Cp = split ? P1 : P0;
  #pragma unroll
  for (int j = 0; j < 4; j++) {
    int gcol = bn * 128 + wn + j * 16 + l15;
    float bv = split ? 0.0f : (float)bias[gcol];
    #pragma unroll
    for (int i = 0; i < 4; i++) {
      int grow = bm * 128 + wm + i * 16 + q * 4;
      #pragma unroll
      for (int r = 0; r < 4; r++)
        Cp[(size_t)(grow + r) * 512 + gcol] = (bf16)(acc[i][j][r] + bv);
    }
  }
}

// Segmented-output GEMM: N = 512*nseg, segment s -> Os (row stride 512).
__global__ __launch_bounds__(256, 2)
void gemm_seg(const bf16* __restrict__ A, const bf16* __restrict__ BT,
              const bf16* __restrict__ bias,
              bf16* __restrict__ O0, bf16* __restrict__ O1, bf16* __restrict__ O2,
              int M, int K)
{
  __shared__ bf16 As[128 * 32];
  __shared__ bf16 Bs[128 * 32];
  const int tid = threadIdx.x;
  int bm, bn; swizzle_bm_bn(bm, bn);
  const int wid = tid >> 6, lane = tid & 63;
  const int wm = (wid >> 1) << 6, wn = (wid & 1) << 6;
  const int l15 = lane & 15, q = lane >> 4;

  f32x4 acc[4][4] = {};

  const bf16* ag = A + (size_t)(bm * 128 + (tid >> 2)) * K + (tid & 3) * 8;
  const bf16* bg = BT + (size_t)(bn * 128 + (tid >> 2)) * K + (tid & 3) * 8;
  const size_t rstep = (size_t)64 * K;
  bf16* asl = As + tid * 8;
  bf16* bsl = Bs + tid * 8;

  for (int k0 = 0; k0 < K; k0 += 32) {
    __syncthreads();
    gload_lds16(ag + k0,          asl);
    gload_lds16(ag + k0 + rstep,  asl + 256 * 8);
    gload_lds16(bg + k0,          bsl);
    gload_lds16(bg + k0 + rstep,  bsl + 256 * 8);
    __syncthreads();

    bf16x8 af[4], bq[4];
    #pragma unroll
    for (int i = 0; i < 4; i++)
      af[i] = *(const bf16x8*)(As + (wm + i * 16 + l15) * 32 + q * 8);
    #pragma unroll
    for (int j = 0; j < 4; j++)
      bq[j] = *(const bf16x8*)(Bs + (wn + j * 16 + l15) * 32 + q * 8);
    #pragma unroll
    for (int i = 0; i < 4; i++)
      #pragma unroll
      for (int j = 0; j < 4; j++)
        acc[i][j] = MFMA(af[i], bq[j], acc[i][j], 0, 0, 0);
  }

  const int seg = (bn * 128) >> 9;
  bf16* Cp = (seg == 0) ? O0 : ((seg == 1) ? O1 : O2);
  const int colb = seg << 9;

  #pragma unroll
  for (int j = 0; j < 4; j++) {
    int gcol = bn * 128 + wn + j * 16 + l15;
    float bv = (float)bias[gcol];
    int lcol = gcol - colb;
    #pragma unroll
    for (int i = 0; i < 4; i++) {
      int grow = bm * 128 + wm + i * 16 + q * 4;
      #pragma unroll
      for (int r = 0; r < 4; r++)
        Cp[(size_t)(grow + r) * 512 + lcol] = (bf16)(acc[i][j][r] + bv);
    }
  }
}

// ---------------------------------------------------------------- flash attn
// Round-6 form (scalar O store). O-repack variant regressed: VGPR 56->76,
// occupancy 37->19%, +12us (r7 post-mortem).
__global__ __launch_bounds__(256, 2)
void flash_attn(const bf16* __restrict__ Q, const bf16* __restrict__ Kf,
                const bf16* __restrict__ Vf, bf16* __restrict__ O,
                int L, int S, int causal)
{
  __shared__ bf16 PL[4][32 * 72];
  const int tid = threadIdx.x, wid = tid >> 6, lane = tid & 63;
  const int m15 = lane & 15, q = lane >> 4;
  const int b = blockIdx.z, h = blockIdx.y;
  const int wq = blockIdx.x * 128 + wid * 32;

  bf16x8 aq[2][2];
  #pragma unroll
  for (int qh = 0; qh < 2; qh++) {
    const bf16* qp = Q + ((size_t)(b * L + wq + qh * 16 + m15)) * D + h * 64 + q * 8;
    aq[qh][0] = *(const bf16x8*)(qp);
    aq[qh][1] = *(const bf16x8*)(qp + 32);
  }
  const size_t bh = (size_t)(b * 8 + h);
  const bf16* kfb = Kf + bh * ((size_t)S * 64);
  const bf16* vfb = Vf + bh * ((size_t)S * 64);

  f32x4 acco[2][4] = {};
  float ls[2][4] = {};

  const int ktmax = causal ? ((wq + 95) >> 6) : (S >> 6);

  bf16x8 kf[4][2];
  #pragma unroll
  for (int nt = 0; nt < 4; nt++)
    #pragma unroll
    for (int c = 0; c < 2; c++)
      kf[nt][c] = *(const bf16x8*)(kfb + ((nt * 2 + c) * 64 + lane) * 8);

  bf16* pl = &PL[wid][0];

  for (int kt = 0; kt < ktmax; kt++) {
    bf16x8 vf[4][2];
    const bf16* vc = vfb + (size_t)kt * 4096;
    #pragma unroll
    for (int nt = 0; nt < 4; nt++)
      #pragma unroll
      for (int c = 0; c < 2; c++)
        vf[nt][c] = *(const bf16x8*)(vc + ((nt * 2 + c) * 64 + lane) * 8);

    f32x4 sc[2][4];
    #pragma unroll
    for (int qh = 0; qh < 2; qh++)
      #pragma unroll
      for (int nt = 0; nt < 4; nt++) {
        f32x4 z = {};
        z = MFMA(aq[qh][0], kf[nt][0], z, 0, 0, 0);
        z = MFMA(aq[qh][1], kf[nt][1], z, 0, 0, 0);
        sc[qh][nt] = z;
      }

    {
      const int knext = (kt + 1 < ktmax) ? kt + 1 : kt;
      const bf16* kc = kfb + (size_t)knext * 4096;
      #pragma unroll
      for (int nt = 0; nt < 4; nt++)
        #pragma unroll
        for (int c = 0; c < 2; c++)
          kf[nt][c] = *(const bf16x8*)(kc + ((nt * 2 + c) * 64 + lane) * 8);
    }

    const bool mask = causal && (kt == ktmax - 1);
    #pragma unroll
    for (int qh = 0; qh < 2; qh++)
      #pragma unroll
      for (int nt = 0; nt < 4; nt++)
        #pragma unroll
        for (int r = 0; r < 4; r++) {
          float s = sc[qh][nt][r] * 0.125f;
          if (mask) {
            int kg = kt * 64 + nt * 16 + m15;
            int qg = wq + qh * 16 + q * 4 + r;
            if (kg > qg) s = -1e30f;
          }
          float p = __expf(s);
          ls[qh][r] += p;
          pl[(qh * 16 + q * 4 + r) * 72 + nt * 16 + m15] = (bf16)p;
        }

    #pragma unroll
    for (int qh = 0; qh < 2; qh++) {
      bf16x8 pa0 = *(const bf16x8*)(pl + (qh * 16 + m15) * 72 + q * 8);
      bf16x8 pa1 = *(const bf16x8*)(pl + (qh * 16 + m15) * 72 + 32 + q * 8);
      #pragma unroll
      for (int nt = 0; nt < 4; nt++) {
        acco[qh][nt] = MFMA(pa0, vf[nt][0], acco[qh][nt], 0, 0, 0);
        acco[qh][nt] = MFMA(pa1, vf[nt][1], acco[qh][nt], 0, 0, 0);
      }
    }
  }

  #pragma unroll
  for (int qh = 0; qh < 2; qh++)
    #pragma unroll
    for (int r = 0; r < 4; r++) {
      float v = ls[qh][r];
      v += __shfl_xor(v, 1); v += __shfl_xor(v, 2);
      v += __shfl_xor(v, 4); v += __shfl_xor(v, 8);
      ls[qh][r] = 1.0f / v;
    }

  #pragma unroll
  for (int qh = 0; qh < 2; qh++)
    #pragma unroll
    for (int nt = 0; nt < 4; nt++)
      #pragma unroll
      for (int r = 0; r < 4; r++)
        O[((size_t)(b * L + wq + qh * 16 + q * 4 + r)) * D + h * 64 + nt * 16 + m15] =
            (bf16)(acco[qh][nt][r] * ls[qh][r]);
}

// Y = LN(X0 (+X1) (+R)) * g + be. X1 nullable (K-split partial sum).
__global__ __launch_bounds__(256)
void add_ln(const bf16* __restrict__ X0, const bf16* __restrict__ X1,
            const bf16* __restrict__ R,
            const bf16* __restrict__ g, const bf16* __restrict__ be,
            bf16* __restrict__ Y, int hasR)
{
  __shared__ float red[4];
  const int row = blockIdx.x, tid = threadIdx.x;
  const bf16* x = X0 + (size_t)row * D;
  float v0 = (float)x[tid], v1 = (float)x[tid + 256];
  if (X1 != nullptr) {
    const bf16* p = X1 + (size_t)row * D;
    v0 += (float)p[tid]; v1 += (float)p[tid + 256];
  }
  if (hasR) {
    const bf16* r = R + (size_t)row * D;
    v0 += (float)r[tid]; v1 += (float)r[tid + 256];
  }
  float s = v0 + v1;
  #pragma unroll
  for (int o = 32; o > 0; o >>= 1) s += __shfl_down(s, o);
  if ((tid & 63) == 0) red[tid >> 6] = s;
  __syncthreads();
  const float mean = (red[0] + red[1] + red[2] + red[3]) * (1.0f / 512.0f);
  __syncthreads();
  const float d0 = v0 - mean, d1 = v1 - mean;
  float sq = d0 * d0 + d1 * d1;
  #pragma unroll
  for (int o = 32; o > 0; o >>= 1) sq += __shfl_down(sq, o);
  if ((tid & 63) == 0) red[tid >> 6] = sq;
  __syncthreads();
  const float var = (red[0] + red[1] + red[2] + red[3]) * (1.0f / 512.0f);
  const float rstd = rsqrtf(var + 1e-5f);
  bf16* y = Y + (size_t)row * D;
  y[tid]       = (bf16)(d0 * rstd * (float)g[tid]       + (float)be[tid]);
  y[tid + 256] = (bf16)(d1 * rstd * (float)g[tid + 256] + (float)be[tid + 256]);
}

// Y = LN( LN(X0+X1+R)*g1+b1 ) * g2 + b2
__global__ __launch_bounds__(256)
void add_lnln(const bf16* __restrict__ X0, const bf16* __restrict__ X1,
              const bf16* __restrict__ R,
              const bf16* __restrict__ g1, const bf16* __restrict__ b1,
              const bf16* __restrict__ g2, const bf16* __restrict__ b2,
              bf16* __restrict__ Y)
{
  __shared__ float red[4];
  const int row = blockIdx.x, tid = threadIdx.x;
  const size_t o = (size_t)row * D;
  float v0 = (float)X0[o + tid] + (float)X1[o + tid] + (float)R[o + tid];
  float v1 = (float)X0[o + tid + 256] + (float)X1[o + tid + 256] + (float)R[o + tid + 256];

  float s = v0 + v1;
  #pragma unroll
  for (int q = 32; q > 0; q >>= 1) s += __shfl_down(s, q);
  if ((tid & 63) == 0) red[tid >> 6] = s;
  __syncthreads();
  const float mean = (red[0] + red[1] + red[2] + red[3]) * (1.0f / 512.0f);
  __syncthreads();
  float d0 = v0 - mean, d1 = v1 - mean;
  float sq = d0 * d0 + d1 * d1;
  #pragma unroll
  for (int q = 32; q > 0; q >>= 1) sq += __shfl_down(sq, q);
  if ((tid & 63) == 0) red[tid >> 6] = sq;
  __syncthreads();
  const float var = (red[0] + red[1] + red[2] + red[3]) * (1.0f / 512.0f);
  const float rstd = rsqrtf(var + 1e-5f);
  float u0 = d0 * rstd * (float)g1[tid]       + (float)b1[tid];
  float u1 = d1 * rstd * (float)g1[tid + 256] + (float)b1[tid + 256];

  __syncthreads();
  float s2 = u0 + u1;
  #pragma unroll
  for (int q = 32; q > 0; q >>= 1) s2 += __shfl_down(s2, q);
  if ((tid & 63) == 0) red[tid >> 6] = s2;
  __syncthreads();
  const float mean2 = (red[0] + red[1] + red[2] + red[3]) * (1.0f / 512.0f);
  __syncthreads();
  float e0 = u0 - mean2, e1 = u1 - mean2;
  float sq2 = e0 * e0 + e1 * e1;
  #pragma unroll
  for (int q = 32; q > 0; q >>= 1) sq2 += __shfl_down(sq2, q);
  if ((tid & 63) == 0) red[tid >> 6] = sq2;
  __syncthreads();
  const float var2 = (red[0] + red[1] + red[2] + red[3]) * (1.0f / 512.0f);
  const float rstd2 = rsqrtf(var2 + 1e-5f);
  bf16* y = Y + o;
  y[tid]       = (bf16)(e0 * rstd2 * (float)g2[tid]       + (float)b2[tid]);
  y[tid + 256] = (bf16)(e1 * rstd2 * (float)g2[tid + 256] + (float)b2[tid + 256]);
}

__global__ __launch_bounds__(256)
void proj_out(const bf16* __restrict__ X, const bf16* __restrict__ Wp,
              const bf16* __restrict__ bp, void* __restrict__ out,
              const int* __restrict__ flag)
{
  __shared__ float part[4][64];
  const int rb = blockIdx.x;
  const int b = rb >> 8, t = rb & 255;
  const int tid = threadIdx.x;
  const bf16* x = X + ((size_t)(b * 512 + 256 + t)) * D;
  const int c = tid & 63, seg = tid >> 6;
  float acc = 0.f;
  for (int k = seg * 128; k < seg * 128 + 128; k++)
    acc += (float)x[k] * (float)Wp[(size_t)k * 64 + c];
  part[seg][c] = acc;
  __syncthreads();
  if (tid < 64) {
    float v = part[0][tid] + part[1][tid] + part[2][tid] + part[3][tid] + (float)bp[tid];
    size_t idx = (size_t)rb * 64 + tid;
    if (*flag) ((float*)out)[idx] = v;
    else       ((bf16*)out)[idx] = (bf16)v;
  }
}

extern "C" void kernel_launch(void* const* d_in, const int* in_sizes, int n_in,
                              void* d_out, int out_size, void* d_ws, size_t ws_size,
                              hipStream_t stream)
{
  (void)in_sizes; (void)n_in; (void)out_size; (void)ws_size;

  char* wsb = (char*)d_ws;
  int* flag = (int*)wsb;
  bf16* w = (bf16*)(wsb + 256);
  size_t off = 0;
  auto alloc = [&](size_t n) { bf16* p = w + off; off += n; return p; };

  bf16* eQKVT = alloc(3 * (size_t)1536 * D);
  bf16* eWoT  = alloc(3 * (size_t)D * D);
  bf16* eW1T  = alloc(3 * (size_t)D * DFF);
  bf16* eW2T  = alloc(3 * (size_t)D * DFF);
  bf16* dQKVT = alloc((size_t)1536 * D);
  bf16* sWoT  = alloc((size_t)D * D);
  bf16* cWqT  = alloc((size_t)D * D);
  bf16* cKVT  = alloc((size_t)1024 * D);
  bf16* cWoT  = alloc((size_t)D * D);
  bf16* dW1T  = alloc((size_t)D * DFF);
  bf16* dW2T  = alloc((size_t)D * DFF);
  bf16* pW    = alloc((size_t)D * 64);
  bf16* e_qkvb  = alloc(3 * 1536);
  bf16* d_sqkvb = alloc(1536);
  bf16* d_ckvb  = alloc(1024);
  bf16* c_ebo = alloc(3 * D);
  bf16* c_eb1 = alloc(3 * DFF); bf16* c_eb2 = alloc(3 * D);
  bf16* c_eg1 = alloc(3 * D);   bf16* c_ebe1 = alloc(3 * D);
  bf16* c_eg2 = alloc(3 * D);   bf16* c_ebe2 = alloc(3 * D);
  bf16* c_eng = alloc(D);       bf16* c_enb = alloc(D);
  bf16* c_dsbo = alloc(D);
  bf16* c_dcbq = alloc(D);      bf16* c_dcbo = alloc(D);
  bf16* c_db1 = alloc(DFF);     bf16* c_db2 = alloc(D);
  bf16* c_dg1 = alloc(D);  bf16* c_dbe1 = alloc(D);
  bf16* c_dg2 = alloc(D);  bf16* c_dbe2 = alloc(D);
  bf16* c_dg3 = alloc(D);  bf16* c_dbe3 = alloc(D);
  bf16* c_dng = alloc(D);  bf16* c_dnb = alloc(D);
  bf16* c_pb  = alloc(64);
  bf16* xe   = alloc((size_t)8192 * D);
  bf16* enco = alloc((size_t)8192 * D);
  bf16* xd0  = alloc((size_t)4096 * D);
  bf16* xd   = alloc((size_t)4096 * D);
  bf16* qb   = alloc((size_t)8192 * D);
  bf16* kb   = alloc((size_t)8192 * D);
  bf16* vb   = alloc((size_t)8192 * D);
  bf16* t0   = alloc((size_t)8192 * D);
  bf16* t1   = alloc((size_t)8192 * D);
  bf16* mid  = qb;

  const dim3 tb(256);

  detect_dtype<<<dim3(1), tb, 0, stream>>>((const unsigned*)d_in[1], flag);

  conv_to_bf16<<<dim3(1024), tb, 0, stream>>>(d_in[1], xe, 8 * 1024 * D, flag);
  conv_to_bf16<<<dim3(1024), tb, 0, stream>>>(d_in[0], xd0, 8 * 512 * D, flag);

  {
    CPack P{};
    int n = 0;
    auto add = [&](int idx, unsigned long long o, bf16* dst, int cnt) {
      P.d[n++] = {d_in[idx], o, dst, cnt, 0};
    };
    add(9, 0, c_ebo, 1536);
    add(11, 0, c_eb1, 6144);  add(13, 0, c_eb2, 1536);
    add(14, 0, c_eg1, 1536);  add(15, 0, c_ebe1, 1536);
    add(16, 0, c_eg2, 1536);  add(17, 0, c_ebe2, 1536);
    add(18, 0, c_eng, 512);   add(19, 0, c_enb, 512);
    add(27, 0, c_dsbo, 512);
    add(29, 0, c_dcbq, 512);  add(35, 0, c_dcbo, 512);
    add(37, 0, c_db1, 2048);  add(39, 0, c_db2, 512);
    add(40, 0, c_dg1, 512);   add(41, 0, c_dbe1, 512);
    add(42, 0, c_dg2, 512);   add(43, 0, c_dbe2, 512);
    add(44, 0, c_dg3, 512);   add(45, 0, c_dbe3, 512);
    add(46, 0, c_dng, 512);   add(47, 0, c_dnb, 512);
    add(48, 0, pW, D * 64);   add(49, 0, c_pb, 64);
    for (int l = 0; l < 3; l++) {
      add(3, (unsigned long long)l * D, e_qkvb + l * 1536, 512);
      add(5, (unsigned long long)l * D, e_qkvb + l * 1536 + 512, 512);
      add(7, (unsigned long long)l * D, e_qkvb + l * 1536 + 1024, 512);
    }
    add(21, 0, d_sqkvb, 512); add(23, 0, d_sqkvb + 512, 512); add(25, 0, d_sqkvb + 1024, 512);
    add(31, 0, d_ckvb, 512);  add(33, 0, d_ckvb + 512, 512);
    conv_batch<<<dim3(24, 1, n), tb, 0, stream>>>(P, flag);
  }

  {
    TPack P{};
    int n = 0;
    for (int l = 0; l < 3; l++) {
      unsigned long long wo = (unsigned long long)l * D * D;
      bf16* dst = eQKVT + (size_t)l * 1536 * D;
      P.d[n++] = {d_in[2], wo, dst};
      P.d[n++] = {d_in[4], wo, dst + 512 * D};
      P.d[n++] = {d_in[6], wo, dst + 1024 * D};
      P.d[n++] = {d_in[8], wo, eWoT + wo};
    }
    P.d[n++] = {d_in[20], 0, dQKVT};
    P.d[n++] = {d_in[22], 0, dQKVT + 512 * D};
    P.d[n++] = {d_in[24], 0, dQKVT + 1024 * D};
    P.d[n++] = {d_in[26], 0, sWoT};
    P.d[n++] = {d_in[28], 0, cWqT};
    P.d[n++] = {d_in[30], 0, cKVT};
    P.d[n++] = {d_in[32], 0, cKVT + 512 * D};
    P.d[n++] = {d_in[34], 0, cWoT};
    transpose_b<<<dim3(8, 8, n), tb, 0, stream>>>(P, D, D, flag);
  }
  {
    TPack P{};
    for (int l = 0; l < 3; l++)
      P.d[l] = {d_in[10], (unsigned long long)l * D * DFF, eW1T + (size_t)l * D * DFF};
    P.d[3] = {d_in[36], 0, dW1T};
    transpose_b<<<dim3(32, 8, 4), tb, 0, stream>>>(P, D, DFF, flag);
  }
  {
    TPack P{};
    for (int l = 0; l < 3; l++)
      P.d[l] = {d_in[12], (unsigned long long)l * D * DFF, eW2T + (size_t)l * D * DFF};
    P.d[3] = {d_in[38], 0, dW2T};
    transpose_b<<<dim3(8, 32, 4), tb, 0, stream>>>(P, DFF, D, flag);
  }

  auto G = [&](const bf16* A, const bf16* BT, const bf16* bias, bf16* C,
               int M, int N, int K, int act) {
    gemm_bt<<<dim3(N / 128, M / 128), tb, 0, stream>>>(A, BT, bias, C, M, N, K, act);
  };
  auto KS = [&](const bf16* A, const bf16* BT, const bf16* bias,
                bf16* P0, bf16* P1, int M, int K) {
    gemm_ks<<<dim3(8, M / 128), tb, 0, stream>>>(A, BT, bias, P0, P1, M, 512, K);
  };
  auto GS = [&](const bf16* A, const bf16* BT, const bf16* bias,
                bf16* O0, bf16* O1, bf16* O2, int M, int N, int K) {
    gemm_seg<<<dim3(N / 128, M / 128), tb, 0, stream>>>(A, BT, bias, O0, O1, O2, M, K);
  };
  auto PK = [&](const bf16* Kp, const bf16* Vp, bf16* Kfp, bf16* Vfp, int S) {
    prep_kv<<<dim3(S / 64, 8, 8), tb, 0, stream>>>(Kp, Vp, Kfp, Vfp, S);
  };
  auto FA = [&](const bf16* Qp, const bf16* Kfp, const bf16* Vfp, bf16* Op,
                int L, int S, int causal) {
    flash_attn<<<dim3(L / 128, 8, 8), tb, 0, stream>>>(Qp, Kfp, Vfp, Op, L, S, causal);
  };
  auto LN = [&](const bf16* X0, const bf16* X1, const bf16* R,
                const bf16* g, const bf16* be, bf16* Y, int hasR, int M) {
    add_ln<<<dim3(M), tb, 0, stream>>>(X0, X1, R, g, be, Y, hasR);
  };

  // ---- encoder: B=8, S=1024 ----
  const int Me = 8192;
  for (int l = 0; l < 3; l++) {
    const size_t wo = (size_t)l * D * D, fo = (size_t)l * D * DFF;
    GS(xe, eQKVT + (size_t)l * 1536 * D, e_qkvb + l * 1536, qb, kb, vb, Me, 1536, D);
    PK(kb, vb, t1, enco, 1024);
    FA(qb, t1, enco, t0, 1024, 1024, 0);
    KS(t0, eWoT + wo, c_ebo + l * D, t1, enco, Me, 512);
    LN(t1, enco, xe, c_eg1 + l * D, c_ebe1 + l * D, xe, 1, Me);
    G(xe, eW1T + fo, c_eb1 + l * DFF, mid, Me, DFF, D, 1);
    KS(mid, eW2T + fo, c_eb2 + l * D, t1, enco, Me, 2048);
    if (l < 2)
      LN(t1, enco, xe, c_eg2 + l * D, c_ebe2 + l * D, xe, 1, Me);
    else
      add_lnln<<<dim3(Me), tb, 0, stream>>>(t1, enco, xe, c_eg2 + 2 * D,
                                            c_ebe2 + 2 * D, c_eng, c_enb, enco);
  }

  // ---- decoder: B=8, L=512 ----
  const int Md = 4096;
  GS(xd0, dQKVT, d_sqkvb, qb, kb, vb, Md, 1536, D);
  PK(kb, vb, t1, xd, 512);
  FA(qb, t1, xd, t0, 512, 512, 1);
  KS(t0, sWoT, c_dsbo, t1, vb, Md, 512);
  LN(t1, vb, xd0, c_dg1, c_dbe1, xd, 1, Md);
  G(xd, cWqT, c_dcbq, qb, Md, D, D, 0);
  GS(enco, cKVT, d_ckvb, kb, vb, nullptr, Me, 1024, D);
  PK(kb, vb, t1, enco, 1024);
  FA(qb, t1, enco, t0, 512, 1024, 0);
  KS(t0, cWoT, c_dcbo, t1, vb, Md, 512);
  LN(t1, vb, xd, c_dg2, c_dbe2, xd, 1, Md);
  G(xd, dW1T, c_db1, mid, Md, DFF, D, 1);
  KS(mid, dW2T, c_db2, t1, vb, Md, 2048);
  add_lnln<<<dim3(Md), tb, 0, stream>>>(t1, vb, xd, c_dg3, c_dbe3, c_dng, c_dnb, xd);
  proj_out<<<dim3(2048), tb, 0, stream>>>(xd, pW, c_pb, d_out, flag);
}

// Round 9
// 894.691 us; speedup vs baseline: 1.2011x; 1.0299x over previous
//
#include <hip/hip_runtime.h>
#include <cstddef>

typedef __bf16 bf16;
typedef __bf16 bf16x8 __attribute__((ext_vector_type(8)));
typedef float f32x4 __attribute__((ext_vector_type(4)));

#define D 512
#define DFF 2048
#define MFMA __builtin_amdgcn_mfma_f32_16x16x32_bf16

__device__ __forceinline__ float load_any(const void* p, size_t i, int f) {
  return f ? ((const float*)p)[i] : (float)((const bf16*)p)[i];
}

// tanh-form GELU via single exp: x*sigmoid(1.5958(x+0.044715x^3)); |err|<3e-3.
__device__ __forceinline__ float fast_gelu(float x) {
  float y = 1.5957691216f * (x + 0.044715f * x * x * x);
  y = fminf(y, 80.0f);
  float e = __expf(y);
  return x * e / (e + 1.0f);
}

__global__ void detect_dtype(const unsigned* __restrict__ x, int* flag) {
  __shared__ int cnt;
  if (threadIdx.x == 0) cnt = 0;
  __syncthreads();
  int local = 0;
  for (int i = threadIdx.x; i < 32768; i += 256) {
    unsigned e = (x[i] >> 7) & 0xFFu;
    if (e >= 160u) local++;
  }
  atomicAdd(&cnt, local);
  __syncthreads();
  if (threadIdx.x == 0) *flag = (cnt > 100) ? 1 : 0;
}

__global__ __launch_bounds__(256)
void conv_to_bf16(const void* __restrict__ src, bf16* __restrict__ dst, int n,
                  const int* __restrict__ flag) {
  const int f = *flag;
  for (int i = blockIdx.x * 256 + threadIdx.x; i < n; i += gridDim.x * 256)
    dst[i] = (bf16)load_any(src, i, f);
}

struct CDesc { const void* src; unsigned long long off; bf16* dst; int n; int pad; };
struct CPack { CDesc d[40]; };
__global__ __launch_bounds__(256)
void conv_batch(CPack P, const int* __restrict__ flag) {
  const CDesc& c = P.d[blockIdx.z];
  const int f = *flag;
  for (int i = blockIdx.x * 256 + threadIdx.x; i < c.n; i += gridDim.x * 256)
    c.dst[i] = (bf16)load_any(c.src, c.off + i, f);
}

struct TDesc { const void* src; unsigned long long off; bf16* dst; };
struct TPack { TDesc d[20]; };
__global__ __launch_bounds__(256)
void transpose_b(TPack P, int Kd, int Nd, const int* __restrict__ flag) {
  __shared__ bf16 tile[64][65];
  const TDesc& t = P.d[blockIdx.z];
  const int f = *flag;
  int tx = threadIdx.x & 63, ty = threadIdx.x >> 6;
  int nb = blockIdx.x * 64, kb = blockIdx.y * 64;
  #pragma unroll
  for (int r = ty; r < 64; r += 4)
    tile[r][tx] = (bf16)load_any(t.src, t.off + (size_t)(kb + r) * Nd + nb + tx, f);
  __syncthreads();
  #pragma unroll
  for (int r = ty; r < 64; r += 4)
    t.dst[(size_t)(nb + r) * Kd + kb + tx] = tile[tx][r];
}

// K,V [B*S,512] -> frag-major Kf,Vf [(b*8+h)][kt][nt][c][lane][8]
__global__ __launch_bounds__(256)
void prep_kv(const bf16* __restrict__ K, const bf16* __restrict__ V,
             bf16* __restrict__ Kf, bf16* __restrict__ Vf, int S)
{
  __shared__ bf16 tile[64][72];
  const int kt = blockIdx.x, h = blockIdx.y, b = blockIdx.z;
  const int t = threadIdx.x;
  const int r = t >> 2, g = t & 3;
  const size_t srcrow = ((size_t)(b * S + kt * 64 + r)) * D + h * 64 + g * 16;
  const size_t bh = (size_t)(b * 8 + h);
  const size_t tbase = (bh * (S >> 6) + kt) * 4096;

  bf16x8 k0 = *(const bf16x8*)(K + srcrow);
  bf16x8 k1 = *(const bf16x8*)(K + srcrow + 8);
  const int nt = r >> 4, m15 = r & 15;
  const int c = g >> 1, qq = (g & 1) * 2;
  *(bf16x8*)(Kf + tbase + (((nt * 2 + c) * 64) + qq * 16 + m15) * 8)       = k0;
  *(bf16x8*)(Kf + tbase + (((nt * 2 + c) * 64) + (qq + 1) * 16 + m15) * 8) = k1;

  bf16x8 v0 = *(const bf16x8*)(V + srcrow);
  bf16x8 v1 = *(const bf16x8*)(V + srcrow + 8);
  #pragma unroll
  for (int u = 0; u < 8; u++) {
    tile[g * 16 + u][r]     = v0[u];
    tile[g * 16 + 8 + u][r] = v1[u];
  }
  __syncthreads();
  #pragma unroll
  for (int s = 0; s < 2; s++) {
    int i = t * 2 + s;
    int lane = i & 63, ntc = i >> 6;
    int vq = lane >> 4, vm = lane & 15;
    int vnt = ntc >> 1, vc = ntc & 1;
    bf16x8 o = *(const bf16x8*)(&tile[vnt * 16 + vm][vc * 32 + vq * 8]);
    *(bf16x8*)(Vf + tbase + (size_t)i * 8) = o;
  }
}

__device__ __forceinline__ void gload_lds16(const bf16* g, bf16* l) {
  __builtin_amdgcn_global_load_lds((const __attribute__((address_space(1))) void*)g,
                                   (__attribute__((address_space(3))) void*)l,
                                   16, 0, 0);
}

// XCD-aware block swizzle: same A row-band -> same XCD (heuristic xcd = lin%8).
__device__ __forceinline__ void swizzle_bm_bn(int& bm, int& bn) {
  int lin = blockIdx.y * gridDim.x + blockIdx.x;
  if ((gridDim.y & 7) == 0) {
    int xcd = lin & 7, j = lin >> 3;
    bn = j % gridDim.x;
    bm = xcd + 8 * (j / gridDim.x);
  } else {
    bn = blockIdx.x; bm = blockIdx.y;
  }
}

// BK=64 K-loop body: two proven BK=32 sub-tiles per barrier pair (r9: halves
// the vmcnt(0)+s_barrier drains, which dominated at K=512 — r8 post-mortem).
// As/Bs are [2][128][32] (16 KB each sub-tile pair). K % 64 == 0.
#define GEMM_K_LOOP(Klen, AG, BG)                                              \
  for (int k0 = 0; k0 < (Klen); k0 += 64) {                                    \
    __syncthreads();                                                           \
    gload_lds16((AG) + k0,              asl);                                  \
    gload_lds16((AG) + k0 + rstep,      asl + 2048);                           \
    gload_lds16((AG) + k0 + 32,         asl + 4096);                           \
    gload_lds16((AG) + k0 + 32 + rstep, asl + 4096 + 2048);                    \
    gload_lds16((BG) + k0,              bsl);                                  \
    gload_lds16((BG) + k0 + rstep,      bsl + 2048);                           \
    gload_lds16((BG) + k0 + 32,         bsl + 4096);                           \
    gload_lds16((BG) + k0 + 32 + rstep, bsl + 4096 + 2048);                    \
    __syncthreads();                                                           \
    _Pragma("unroll")                                                          \
    for (int s = 0; s < 2; s++) {                                              \
      bf16x8 af[4], bq[4];                                                     \
      _Pragma("unroll")                                                        \
      for (int i = 0; i < 4; i++)                                              \
        af[i] = *(const bf16x8*)(As + s * 4096 + (wm + i * 16 + l15) * 32 + q * 8); \
      _Pragma("unroll")                                                        \
      for (int j = 0; j < 4; j++)                                              \
        bq[j] = *(const bf16x8*)(Bs + s * 4096 + (wn + j * 16 + l15) * 32 + q * 8); \
      _Pragma("unroll")                                                        \
      for (int i = 0; i < 4; i++)                                              \
        _Pragma("unroll")                                                      \
        for (int j = 0; j < 4; j++)                                            \
          acc[i][j] = MFMA(af[i], bq[j], acc[i][j], 0, 0, 0);                  \
    }                                                                          \
  }

// C[M,N] = act(A @ B + bias), B as BT[N,K]. Scalar epilogue (r7 lesson: LDS
// repack costs VGPR/occupancy more than store coalescing wins).
__global__ __launch_bounds__(256, 2)
void gemm_bt(const bf16* __restrict__ A, const bf16* __restrict__ BT,
             const bf16* __restrict__ bias, bf16* __restrict__ C,
             int M, int N, int K, int act)
{
  __shared__ bf16 As[2 * 128 * 32];
  __shared__ bf16 Bs[2 * 128 * 32];
  const int tid = threadIdx.x;
  int bm, bn; swizzle_bm_bn(bm, bn);
  const int wid = tid >> 6, lane = tid & 63;
  const int wm = (wid >> 1) << 6, wn = (wid & 1) << 6;
  const int l15 = lane & 15, q = lane >> 4;

  f32x4 acc[4][4] = {};

  const bf16* ag = A + (size_t)(bm * 128 + (tid >> 2)) * K + (tid & 3) * 8;
  const bf16* bg = BT + (size_t)(bn * 128 + (tid >> 2)) * K + (tid & 3) * 8;
  const size_t rstep = (size_t)64 * K;
  bf16* asl = As + tid * 8;
  bf16* bsl = Bs + tid * 8;

  GEMM_K_LOOP(K, ag, bg)

  #pragma unroll
  for (int j = 0; j < 4; j++) {
    int gcol = bn * 128 + wn + j * 16 + l15;
    float bv = (float)bias[gcol];
    #pragma unroll
    for (int i = 0; i < 4; i++) {
      int grow = bm * 128 + wm + i * 16 + q * 4;
      #pragma unroll
      for (int r = 0; r < 4; r++) {
        float v = acc[i][j][r] + bv;
        if (act == 1) v = fast_gelu(v);
        C[(size_t)(grow + r) * N + gcol] = (bf16)v;
      }
    }
  }
}

// K-split GEMM (ksplit=2): N==512. split0 -> P0 (+bias), split1 -> P1.
__global__ __launch_bounds__(256, 2)
void gemm_ks(const bf16* __restrict__ A, const bf16* __restrict__ BT,
             const bf16* __restrict__ bias, bf16* __restrict__ P0,
             bf16* __restrict__ P1, int M, int N, int K)
{
  __shared__ bf16 As[2 * 128 * 32];
  __shared__ bf16 Bs[2 * 128 * 32];
  const int tid = threadIdx.x;
  int bm, bnl; swizzle_bm_bn(bm, bnl);
  const int bn = bnl >> 1, split = bnl & 1;
  const int Kh = K >> 1, kbase = split * Kh;
  const int wid = tid >> 6, lane = tid & 63;
  const int wm = (wid >> 1) << 6, wn = (wid & 1) << 6;
  const int l15 = lane & 15, q = lane >> 4;

  f32x4 acc[4][4] = {};

  const bf16* ag = A + (size_t)(bm * 128 + (tid >> 2)) * K + kbase + (tid & 3) * 8;
  const bf16* bg = BT + (size_t)(bn * 128 + (tid >> 2)) * K + kbase + (tid & 3) * 8;
  const size_t rstep = (size_t)64 * K;
  bf16* asl = As + tid * 8;
  bf16* bsl = Bs + tid * 8;

  GEMM_K_LOOP(Kh, ag, bg)

  bf16* Cp = split ? P1 : P0;
  #pragma unroll
  for (int j = 0; j < 4; j++) {
    int gcol = bn * 128 + wn + j * 16 + l15;
    float bv = split ? 0.0f : (float)bias[gcol];
    #pragma unroll
    for (int i = 0; i < 4; i++) {
      int grow = bm * 128 + wm + i * 16 + q * 4;
      #pragma unroll
      for (int r = 0; r < 4; r++)
        Cp[(size_t)(grow + r) * 512 + gcol] = (bf16)(acc[i][j][r] + bv);
    }
  }
}

// Segmented-output GEMM: N = 512*nseg, segment s -> Os (row stride 512).
__global__ __launch_bounds__(256, 2)
void gemm_seg(const bf16* __restrict__ A, const bf16* __restrict__ BT,
              const bf16* __restrict__ bias,
              bf16* __restrict__ O0, bf16* __restrict__ O1, bf16* __restrict__ O2,
              int M, int K)
{
  __shared__ bf16 As[2 * 128 * 32];
  __shared__ bf16 Bs[2 * 128 * 32];
  const int tid = threadIdx.x;
  int bm, bn; swizzle_bm_bn(bm, bn);
  const int wid = tid >> 6, lane = tid & 63;
  const int wm = (wid >> 1) << 6, wn = (wid & 1) << 6;
  const int l15 = lane & 15, q = lane >> 4;

  f32x4 acc[4][4] = {};

  const bf16* ag = A + (size_t)(bm * 128 + (tid >> 2)) * K + (tid & 3) * 8;
  const bf16* bg = BT + (size_t)(bn * 128 + (tid >> 2)) * K + (tid & 3) * 8;
  const size_t rstep = (size_t)64 * K;
  bf16* asl = As + tid * 8;
  bf16* bsl = Bs + tid * 8;

  GEMM_K_LOOP(K, ag, bg)

  const int seg = (bn * 128) >> 9;
  bf16* Cp = (seg == 0) ? O0 : ((seg == 1) ? O1 : O2);
  const int colb = seg << 9;

  #pragma unroll
  for (int j = 0; j < 4; j++) {
    int gcol = bn * 128 + wn + j * 16 + l15;
    float bv = (float)bias[gcol];
    int lcol = gcol - colb;
    #pragma unroll
    for (int i = 0; i < 4; i++) {
      int grow = bm * 128 + wm + i * 16 + q * 4;
      #pragma unroll
      for (int r = 0; r < 4; r++)
        Cp[(size_t)(grow + r) * 512 + lcol] = (bf16)(acc[i][j][r] + bv);
    }
  }
}

// ---------------------------------------------------------------- flash attn
// Round-6 form (scalar O store): O-repack variant regressed (r7 post-mortem).
__global__ __launch_bounds__(256, 2)
void flash_attn(const bf16* __restrict__ Q, const bf16* __restrict__ Kf,
                const bf16* __restrict__ Vf, bf16* __restrict__ O,
                int L, int S, int causal)
{
  __shared__ bf16 PL[4][32 * 72];
  const int tid = threadIdx.x, wid = tid >> 6, lane = tid & 63;
  const int m15 = lane & 15, q = lane >> 4;
  const int b = blockIdx.z, h = blockIdx.y;
  const int wq = blockIdx.x * 128 + wid * 32;

  bf16x8 aq[2][2];
  #pragma unroll
  for (int qh = 0; qh < 2; qh++) {
    const bf16* qp = Q + ((size_t)(b * L + wq + qh * 16 + m15)) * D + h * 64 + q * 8;
    aq[qh][0] = *(const bf16x8*)(qp);
    aq[qh][1] = *(const bf16x8*)(qp + 32);
  }
  const size_t bh = (size_t)(b * 8 + h);
  const bf16* kfb = Kf + bh * ((size_t)S * 64);
  const bf16* vfb = Vf + bh * ((size_t)S * 64);

  f32x4 acco[2][4] = {};
  float ls[2][4] = {};

  const int ktmax = causal ? ((wq + 95) >> 6) : (S >> 6);

  bf16x8 kf[4][2];
  #pragma unroll
  for (int nt = 0; nt < 4; nt++)
    #pragma unroll
    for (int c = 0; c < 2; c++)
      kf[nt][c] = *(const bf16x8*)(kfb + ((nt * 2 + c) * 64 + lane) * 8);

  bf16* pl = &PL[wid][0];

  for (int kt = 0; kt < ktmax; kt++) {
    bf16x8 vf[4][2];
    const bf16* vc = vfb + (size_t)kt * 4096;
    #pragma unroll
    for (int nt = 0; nt < 4; nt++)
      #pragma unroll
      for (int c = 0; c < 2; c++)
        vf[nt][c] = *(const bf16x8*)(vc + ((nt * 2 + c) * 64 + lane) * 8);

    f32x4 sc[2][4];
    #pragma unroll
    for (int qh = 0; qh < 2; qh++)
      #pragma unroll
      for (int nt = 0; nt < 4; nt++) {
        f32x4 z = {};
        z = MFMA(aq[qh][0], kf[nt][0], z, 0, 0, 0);
        z = MFMA(aq[qh][1], kf[nt][1], z, 0, 0, 0);
        sc[qh][nt] = z;
      }

    {
      const int knext = (kt + 1 < ktmax) ? kt + 1 : kt;
      const bf16* kc = kfb + (size_t)knext * 4096;
      #pragma unroll
      for (int nt = 0; nt < 4; nt++)
        #pragma unroll
        for (int c = 0; c < 2; c++)
          kf[nt][c] = *(const bf16x8*)(kc + ((nt * 2 + c) * 64 + lane) * 8);
    }

    const bool mask = causal && (kt == ktmax - 1);
    #pragma unroll
    for (int qh = 0; qh < 2; qh++)
      #pragma unroll
      for (int nt = 0; nt < 4; nt++)
        #pragma unroll
        for (int r = 0; r < 4; r++) {
          float s = sc[qh][nt][r] * 0.125f;
          if (mask) {
            int kg = kt * 64 + nt * 16 + m15;
            int qg = wq + qh * 16 + q * 4 + r;
            if (kg > qg) s = -1e30f;
          }
          float p = __expf(s);
          ls[qh][r] += p;
          pl[(qh * 16 + q * 4 + r) * 72 + nt * 16 + m15] = (bf16)p;
        }

    #pragma unroll
    for (int qh = 0; qh < 2; qh++) {
      bf16x8 pa0 = *(const bf16x8*)(pl + (qh * 16 + m15) * 72 + q * 8);
      bf16x8 pa1 = *(const bf16x8*)(pl + (qh * 16 + m15) * 72 + 32 + q * 8);
      #pragma unroll
      for (int nt = 0; nt < 4; nt++) {
        acco[qh][nt] = MFMA(pa0, vf[nt][0], acco[qh][nt], 0, 0, 0);
        acco[qh][nt] = MFMA(pa1, vf[nt][1], acco[qh][nt], 0, 0, 0);
      }
    }
  }

  #pragma unroll
  for (int qh = 0; qh < 2; qh++)
    #pragma unroll
    for (int r = 0; r < 4; r++) {
      float v = ls[qh][r];
      v += __shfl_xor(v, 1); v += __shfl_xor(v, 2);
      v += __shfl_xor(v, 4); v += __shfl_xor(v, 8);
      ls[qh][r] = 1.0f / v;
    }

  #pragma unroll
  for (int qh = 0; qh < 2; qh++)
    #pragma unroll
    for (int nt = 0; nt < 4; nt++)
      #pragma unroll
      for (int r = 0; r < 4; r++)
        O[((size_t)(b * L + wq + qh * 16 + q * 4 + r)) * D + h * 64 + nt * 16 + m15] =
            (bf16)(acco[qh][nt][r] * ls[qh][r]);
}

// Y = LN(X0 (+X1) (+R)) * g + be. X1 nullable (K-split partial sum).
__global__ __launch_bounds__(256)
void add_ln(const bf16* __restrict__ X0, const bf16* __restrict__ X1,
            const bf16* __restrict__ R,
            const bf16* __restrict__ g, const bf16* __restrict__ be,
            bf16* __restrict__ Y, int hasR)
{
  __shared__ float red[4];
  const int row = blockIdx.x, tid = threadIdx.x;
  const bf16* x = X0 + (size_t)row * D;
  float v0 = (float)x[tid], v1 = (float)x[tid + 256];
  if (X1 != nullptr) {
    const bf16* p = X1 + (size_t)row * D;
    v0 += (float)p[tid]; v1 += (float)p[tid + 256];
  }
  if (hasR) {
    const bf16* r = R + (size_t)row * D;
    v0 += (float)r[tid]; v1 += (float)r[tid + 256];
  }
  float s = v0 + v1;
  #pragma unroll
  for (int o = 32; o > 0; o >>= 1) s += __shfl_down(s, o);
  if ((tid & 63) == 0) red[tid >> 6] = s;
  __syncthreads();
  const float mean = (red[0] + red[1] + red[2] + red[3]) * (1.0f / 512.0f);
  __syncthreads();
  const float d0 = v0 - mean, d1 = v1 - mean;
  float sq = d0 * d0 + d1 * d1;
  #pragma unroll
  for (int o = 32; o > 0; o >>= 1) sq += __shfl_down(sq, o);
  if ((tid & 63) == 0) red[tid >> 6] = sq;
  __syncthreads();
  const float var = (red[0] + red[1] + red[2] + red[3]) * (1.0f / 512.0f);
  const float rstd = rsqrtf(var + 1e-5f);
  bf16* y = Y + (size_t)row * D;
  y[tid]       = (bf16)(d0 * rstd * (float)g[tid]       + (float)be[tid]);
  y[tid + 256] = (bf16)(d1 * rstd * (float)g[tid + 256] + (float)be[tid + 256]);
}

// Y = LN( LN(X0+X1+R)*g1+b1 ) * g2 + b2
__global__ __launch_bounds__(256)
void add_lnln(const bf16* __restrict__ X0, const bf16* __restrict__ X1,
              const bf16* __restrict__ R,
              const bf16* __restrict__ g1, const bf16* __restrict__ b1,
              const bf16* __restrict__ g2, const bf16* __restrict__ b2,
              bf16* __restrict__ Y)
{
  __shared__ float red[4];
  const int row = blockIdx.x, tid = threadIdx.x;
  const size_t o = (size_t)row * D;
  float v0 = (float)X0[o + tid] + (float)X1[o + tid] + (float)R[o + tid];
  float v1 = (float)X0[o + tid + 256] + (float)X1[o + tid + 256] + (float)R[o + tid + 256];

  float s = v0 + v1;
  #pragma unroll
  for (int q = 32; q > 0; q >>= 1) s += __shfl_down(s, q);
  if ((tid & 63) == 0) red[tid >> 6] = s;
  __syncthreads();
  const float mean = (red[0] + red[1] + red[2] + red[3]) * (1.0f / 512.0f);
  __syncthreads();
  float d0 = v0 - mean, d1 = v1 - mean;
  float sq = d0 * d0 + d1 * d1;
  #pragma unroll
  for (int q = 32; q > 0; q >>= 1) sq += __shfl_down(sq, q);
  if ((tid & 63) == 0) red[tid >> 6] = sq;
  __syncthreads();
  const float var = (red[0] + red[1] + red[2] + red[3]) * (1.0f / 512.0f);
  const float rstd = rsqrtf(var + 1e-5f);
  float u0 = d0 * rstd * (float)g1[tid]       + (float)b1[tid];
  float u1 = d1 * rstd * (float)g1[tid + 256] + (float)b1[tid + 256];

  __syncthreads();
  float s2 = u0 + u1;
  #pragma unroll
  for (int q = 32; q > 0; q >>= 1) s2 += __shfl_down(s2, q);
  if ((tid & 63) == 0) red[tid >> 6] = s2;
  __syncthreads();
  const float mean2 = (red[0] + red[1] + red[2] + red[3]) * (1.0f / 512.0f);
  __syncthreads();
  float e0 = u0 - mean2, e1 = u1 - mean2;
  float sq2 = e0 * e0 + e1 * e1;
  #pragma unroll
  for (int q = 32; q > 0; q >>= 1) sq2 += __shfl_down(sq2, q);
  if ((tid & 63) == 0) red[tid >> 6] = sq2;
  __syncthreads();
  const float var2 = (red[0] + red[1] + red[2] + red[3]) * (1.0f / 512.0f);
  const float rstd2 = rsqrtf(var2 + 1e-5f);
  bf16* y = Y + o;
  y[tid]       = (bf16)(e0 * rstd2 * (float)g2[tid]       + (float)b2[tid]);
  y[tid + 256] = (bf16)(e1 * rstd2 * (float)g2[tid + 256] + (float)b2[tid + 256]);
}

__global__ __launch_bounds__(256)
void proj_out(const bf16* __restrict__ X, const bf16* __restrict__ Wp,
              const bf16* __restrict__ bp, void* __restrict__ out,
              const int* __restrict__ flag)
{
  __shared__ float part[4][64];
  const int rb = blockIdx.x;
  const int b = rb >> 8, t = rb & 255;
  const int tid = threadIdx.x;
  const bf16* x = X + ((size_t)(b * 512 + 256 + t)) * D;
  const int c = tid & 63, seg = tid >> 6;
  float acc = 0.f;
  for (int k = seg * 128; k < seg * 128 + 128; k++)
    acc += (float)x[k] * (float)Wp[(size_t)k * 64 + c];
  part[seg][c] = acc;
  __syncthreads();
  if (tid < 64) {
    float v = part[0][tid] + part[1][tid] + part[2][tid] + part[3][tid] + (float)bp[tid];
    size_t idx = (size_t)rb * 64 + tid;
    if (*flag) ((float*)out)[idx] = v;
    else       ((bf16*)out)[idx] = (bf16)v;
  }
}

extern "C" void kernel_launch(void* const* d_in, const int* in_sizes, int n_in,
                              void* d_out, int out_size, void* d_ws, size_t ws_size,
                              hipStream_t stream)
{
  (void)in_sizes; (void)n_in; (void)out_size; (void)ws_size;

  char* wsb = (char*)d_ws;
  int* flag = (int*)wsb;
  bf16* w = (bf16*)(wsb + 256);
  size_t off = 0;
  auto alloc = [&](size_t n) { bf16* p = w + off; off += n; return p; };

  bf16* eQKVT = alloc(3 * (size_t)1536 * D);
  bf16* eWoT  = alloc(3 * (size_t)D * D);
  bf16* eW1T  = alloc(3 * (size_t)D * DFF);
  bf16* eW2T  = alloc(3 * (size_t)D * DFF);
  bf16* dQKVT = alloc((size_t)1536 * D);
  bf16* sWoT  = alloc((size_t)D * D);
  bf16* cWqT  = alloc((size_t)D * D);
  bf16* cKVT  = alloc((size_t)1024 * D);
  bf16* cWoT  = alloc((size_t)D * D);
  bf16* dW1T  = alloc((size_t)D * DFF);
  bf16* dW2T  = alloc((size_t)D * DFF);
  bf16* pW    = alloc((size_t)D * 64);
  bf16* e_qkvb  = alloc(3 * 1536);
  bf16* d_sqkvb = alloc(1536);
  bf16* d_ckvb  = alloc(1024);
  bf16* c_ebo = alloc(3 * D);
  bf16* c_eb1 = alloc(3 * DFF); bf16* c_eb2 = alloc(3 * D);
  bf16* c_eg1 = alloc(3 * D);   bf16* c_ebe1 = alloc(3 * D);
  bf16* c_eg2 = alloc(3 * D);   bf16* c_ebe2 = alloc(3 * D);
  bf16* c_eng = alloc(D);       bf16* c_enb = alloc(D);
  bf16* c_dsbo = alloc(D);
  bf16* c_dcbq = alloc(D);      bf16* c_dcbo = alloc(D);
  bf16* c_db1 = alloc(DFF);     bf16* c_db2 = alloc(D);
  bf16* c_dg1 = alloc(D);  bf16* c_dbe1 = alloc(D);
  bf16* c_dg2 = alloc(D);  bf16* c_dbe2 = alloc(D);
  bf16* c_dg3 = alloc(D);  bf16* c_dbe3 = alloc(D);
  bf16* c_dng = alloc(D);  bf16* c_dnb = alloc(D);
  bf16* c_pb  = alloc(64);
  bf16* xe   = alloc((size_t)8192 * D);
  bf16* enco = alloc((size_t)8192 * D);
  bf16* xd0  = alloc((size_t)4096 * D);
  bf16* xd   = alloc((size_t)4096 * D);
  bf16* qb   = alloc((size_t)8192 * D);
  bf16* kb   = alloc((size_t)8192 * D);
  bf16* vb   = alloc((size_t)8192 * D);
  bf16* t0   = alloc((size_t)8192 * D);
  bf16* t1   = alloc((size_t)8192 * D);
  bf16* mid  = qb;

  const dim3 tb(256);

  detect_dtype<<<dim3(1), tb, 0, stream>>>((const unsigned*)d_in[1], flag);

  conv_to_bf16<<<dim3(1024), tb, 0, stream>>>(d_in[1], xe, 8 * 1024 * D, flag);
  conv_to_bf16<<<dim3(1024), tb, 0, stream>>>(d_in[0], xd0, 8 * 512 * D, flag);

  {
    CPack P{};
    int n = 0;
    auto add = [&](int idx, unsigned long long o, bf16* dst, int cnt) {
      P.d[n++] = {d_in[idx], o, dst, cnt, 0};
    };
    add(9, 0, c_ebo, 1536);
    add(11, 0, c_eb1, 6144);  add(13, 0, c_eb2, 1536);
    add(14, 0, c_eg1, 1536);  add(15, 0, c_ebe1, 1536);
    add(16, 0, c_eg2, 1536);  add(17, 0, c_ebe2, 1536);
    add(18, 0, c_eng, 512);   add(19, 0, c_enb, 512);
    add(27, 0, c_dsbo, 512);
    add(29, 0, c_dcbq, 512);  add(35, 0, c_dcbo, 512);
    add(37, 0, c_db1, 2048);  add(39, 0, c_db2, 512);
    add(40, 0, c_dg1, 512);   add(41, 0, c_dbe1, 512);
    add(42, 0, c_dg2, 512);   add(43, 0, c_dbe2, 512);
    add(44, 0, c_dg3, 512);   add(45, 0, c_dbe3, 512);
    add(46, 0, c_dng, 512);   add(47, 0, c_dnb, 512);
    add(48, 0, pW, D * 64);   add(49, 0, c_pb, 64);
    for (int l = 0; l < 3; l++) {
      add(3, (unsigned long long)l * D, e_qkvb + l * 1536, 512);
      add(5, (unsigned long long)l * D, e_qkvb + l * 1536 + 512, 512);
      add(7, (unsigned long long)l * D, e_qkvb + l * 1536 + 1024, 512);
    }
    add(21, 0, d_sqkvb, 512); add(23, 0, d_sqkvb + 512, 512); add(25, 0, d_sqkvb + 1024, 512);
    add(31, 0, d_ckvb, 512);  add(33, 0, d_ckvb + 512, 512);
    conv_batch<<<dim3(24, 1, n), tb, 0, stream>>>(P, flag);
  }

  {
    TPack P{};
    int n = 0;
    for (int l = 0; l < 3; l++) {
      unsigned long long wo = (unsigned long long)l * D * D;
      bf16* dst = eQKVT + (size_t)l * 1536 * D;
      P.d[n++] = {d_in[2], wo, dst};
      P.d[n++] = {d_in[4], wo, dst + 512 * D};
      P.d[n++] = {d_in[6], wo, dst + 1024 * D};
      P.d[n++] = {d_in[8], wo, eWoT + wo};
    }
    P.d[n++] = {d_in[20], 0, dQKVT};
    P.d[n++] = {d_in[22], 0, dQKVT + 512 * D};
    P.d[n++] = {d_in[24], 0, dQKVT + 1024 * D};
    P.d[n++] = {d_in[26], 0, sWoT};
    P.d[n++] = {d_in[28], 0, cWqT};
    P.d[n++] = {d_in[30], 0, cKVT};
    P.d[n++] = {d_in[32], 0, cKVT + 512 * D};
    P.d[n++] = {d_in[34], 0, cWoT};
    transpose_b<<<dim3(8, 8, n), tb, 0, stream>>>(P, D, D, flag);
  }
  {
    TPack P{};
    for (int l = 0; l < 3; l++)
      P.d[l] = {d_in[10], (unsigned long long)l * D * DFF, eW1T + (size_t)l * D * DFF};
    P.d[3] = {d_in[36], 0, dW1T};
    transpose_b<<<dim3(32, 8, 4), tb, 0, stream>>>(P, D, DFF, flag);
  }
  {
    TPack P{};
    for (int l = 0; l < 3; l++)
      P.d[l] = {d_in[12], (unsigned long long)l * D * DFF, eW2T + (size_t)l * D * DFF};
    P.d[3] = {d_in[38], 0, dW2T};
    transpose_b<<<dim3(8, 32, 4), tb, 0, stream>>>(P, DFF, D, flag);
  }

  auto G = [&](const bf16* A, const bf16* BT, const bf16* bias, bf16* C,
               int M, int N, int K, int act) {
    gemm_bt<<<dim3(N / 128, M / 128), tb, 0, stream>>>(A, BT, bias, C, M, N, K, act);
  };
  auto KS = [&](const bf16* A, const bf16* BT, const bf16* bias,
                bf16* P0, bf16* P1, int M, int K) {
    gemm_ks<<<dim3(8, M / 128), tb, 0, stream>>>(A, BT, bias, P0, P1, M, 512, K);
  };
  auto GS = [&](const bf16* A, const bf16* BT, const bf16* bias,
                bf16* O0, bf16* O1, bf16* O2, int M, int N, int K) {
    gemm_seg<<<dim3(N / 128, M / 128), tb, 0, stream>>>(A, BT, bias, O0, O1, O2, M, K);
  };
  auto PK = [&](const bf16* Kp, const bf16* Vp, bf16* Kfp, bf16* Vfp, int S) {
    prep_kv<<<dim3(S / 64, 8, 8), tb, 0, stream>>>(Kp, Vp, Kfp, Vfp, S);
  };
  auto FA = [&](const bf16* Qp, const bf16* Kfp, const bf16* Vfp, bf16* Op,
                int L, int S, int causal) {
    flash_attn<<<dim3(L / 128, 8, 8), tb, 0, stream>>>(Qp, Kfp, Vfp, Op, L, S, causal);
  };
  auto LN = [&](const bf16* X0, const bf16* X1, const bf16* R,
                const bf16* g, const bf16* be, bf16* Y, int hasR, int M) {
    add_ln<<<dim3(M), tb, 0, stream>>>(X0, X1, R, g, be, Y, hasR);
  };

  // ---- encoder: B=8, S=1024 ----
  const int Me = 8192;
  for (int l = 0; l < 3; l++) {
    const size_t wo = (size_t)l * D * D, fo = (size_t)l * D * DFF;
    GS(xe, eQKVT + (size_t)l * 1536 * D, e_qkvb + l * 1536, qb, kb, vb, Me, 1536, D);
    PK(kb, vb, t1, enco, 1024);
    FA(qb, t1, enco, t0, 1024, 1024, 0);
    KS(t0, eWoT + wo, c_ebo + l * D, t1, enco, Me, 512);
    LN(t1, enco, xe, c_eg1 + l * D, c_ebe1 + l * D, xe, 1, Me);
    G(xe, eW1T + fo, c_eb1 + l * DFF, mid, Me, DFF, D, 1);
    KS(mid, eW2T + fo, c_eb2 + l * D, t1, enco, Me, 2048);
    if (l < 2)
      LN(t1, enco, xe, c_eg2 + l * D, c_ebe2 + l * D, xe, 1, Me);
    else
      add_lnln<<<dim3(Me), tb, 0, stream>>>(t1, enco, xe, c_eg2 + 2 * D,
                                            c_ebe2 + 2 * D, c_eng, c_enb, enco);
  }

  // ---- decoder: B=8, L=512 ----
  const int Md = 4096;
  GS(xd0, dQKVT, d_sqkvb, qb, kb, vb, Md, 1536, D);
  PK(kb, vb, t1, xd, 512);
  FA(qb, t1, xd, t0, 512, 512, 1);
  KS(t0, sWoT, c_dsbo, t1, vb, Md, 512);
  LN(t1, vb, xd0, c_dg1, c_dbe1, xd, 1, Md);
  G(xd, cWqT, c_dcbq, qb, Md, D, D, 0);
  GS(enco, cKVT, d_ckvb, kb, vb, nullptr, Me, 1024, D);
  PK(kb, vb, t1, enco, 1024);
  FA(qb, t1, enco, t0, 512, 1024, 0);
  KS(t0, cWoT, c_dcbo, t1, vb, Md, 512);
  LN(t1, vb, xd, c_dg2, c_dbe2, xd, 1, Md);
  G(xd, dW1T, c_db1, mid, Md, DFF, D, 1);
  KS(mid, dW2T, c_db2, t1, vb, Md, 2048);
  add_lnln<<<dim3(Md), tb, 0, stream>>>(t1, vb, xd, c_dg3, c_dbe3, c_dng, c_dnb, xd);
  proj_out<<<dim3(2048), tb, 0, stream>>>(xd, pW, c_pb, d_out, flag);
}